// Round 1
// baseline (56077.502 us; speedup 1.0000x reference)
//
#include <hip/hip_runtime.h>
#include <math.h>

#define LOG2PI 1.8378770664093453f
#define TILE 128
#define BKK 8

// ---------------------------------------------------------------------------
// Generic fp32 tiled GEMM: C(MxN) = A(MxK) @ Bm(KxN), with fused epilogues.
// EPI 0: store
// EPI 1: H1  -> a1 = tanh(acc + sc0*p2[n] + p0[idx]); C=a1; C2=(1-a1^2)*p1[idx]
// EPI 2: H2  -> rows < halfM: tanh(acc + p3[n]) else acc  (stacked a/ta GEMM)
// EPI 3: bias-> acc + p3[n]
// EPI 4: Gc  -> acc + p0[m]*p2[n] + p3[n]
// ---------------------------------------------------------------------------
template<int EPI>
__global__ __launch_bounds__(256) void gemm_k(
    const float* __restrict__ A, int lda,
    const float* __restrict__ Bm, int ldb,
    float* __restrict__ C, int ldc,
    int M, int N, int K,
    const float* __restrict__ p0,
    const float* __restrict__ p1,
    const float* __restrict__ p2,
    const float* __restrict__ p3,
    float sc0, float* __restrict__ C2, int halfM)
{
    __shared__ float As[BKK][TILE];
    __shared__ float Bs[BKK][TILE];
    const int tid = threadIdx.x;
    const int tx = tid & 15, ty = tid >> 4;
    const int m0 = blockIdx.y * TILE, n0 = blockIdx.x * TILE;

    float acc[8][8];
    #pragma unroll
    for (int i = 0; i < 8; ++i)
        #pragma unroll
        for (int j = 0; j < 8; ++j) acc[i][j] = 0.f;

    const int arow = tid >> 1;         // 0..127
    const int ak0  = (tid & 1) * 4;    // 0 or 4
    const int bkr  = tid >> 5;         // 0..7
    const int bcol = (tid & 31) * 4;   // 0..124
    const float* Arow = A + (size_t)(m0 + arow) * lda;

    for (int k0 = 0; k0 < K; k0 += BKK) {
        #pragma unroll
        for (int j = 0; j < 4; ++j) {
            int k = k0 + ak0 + j;
            As[ak0 + j][arow] = (k < K) ? Arow[k] : 0.f;
        }
        {
            int kb = k0 + bkr;
            const float* Brow = Bm + (size_t)kb * ldb + n0;
            #pragma unroll
            for (int j = 0; j < 4; ++j) {
                int n = n0 + bcol + j;
                Bs[bkr][bcol + j] = (kb < K && n < N) ? Brow[bcol + j] : 0.f;
            }
        }
        __syncthreads();
        #pragma unroll
        for (int kk = 0; kk < BKK; ++kk) {
            float4 a0 = *(const float4*)&As[kk][ty * 8];
            float4 a1 = *(const float4*)&As[kk][ty * 8 + 4];
            float4 b0 = *(const float4*)&Bs[kk][tx * 8];
            float4 b1 = *(const float4*)&Bs[kk][tx * 8 + 4];
            float ar[8] = {a0.x,a0.y,a0.z,a0.w,a1.x,a1.y,a1.z,a1.w};
            float br[8] = {b0.x,b0.y,b0.z,b0.w,b1.x,b1.y,b1.z,b1.w};
            #pragma unroll
            for (int i = 0; i < 8; ++i)
                #pragma unroll
                for (int j = 0; j < 8; ++j)
                    acc[i][j] = fmaf(ar[i], br[j], acc[i][j]);
        }
        __syncthreads();
    }

    #pragma unroll
    for (int i = 0; i < 8; ++i) {
        size_t m = (size_t)m0 + ty * 8 + i;
        #pragma unroll
        for (int j = 0; j < 8; ++j) {
            int n = n0 + tx * 8 + j;
            if (n >= N) continue;
            size_t idx = m * (size_t)ldc + n;
            float v = acc[i][j];
            if constexpr (EPI == 0) {
                C[idx] = v;
            } else if constexpr (EPI == 1) {
                float a = tanhf(v + sc0 * p2[n] + p0[idx]);
                C[idx]  = a;
                C2[idx] = (1.f - a * a) * p1[idx];
            } else if constexpr (EPI == 2) {
                C[idx] = ((int)m < halfM) ? tanhf(v + p3[n]) : v;
            } else if constexpr (EPI == 3) {
                C[idx] = v + p3[n];
            } else if constexpr (EPI == 4) {
                C[idx] = v + p0[m] * p2[n] + p3[n];
            }
        }
    }
}

// out[i] = x0[i] + sum_{j<nk} c_j * k_j[i]   (float4-vectorized)
__global__ __launch_bounds__(256) void axpy5(
    float4* __restrict__ out, const float4* __restrict__ x0,
    const float4* __restrict__ k0, const float4* __restrict__ k1,
    const float4* __restrict__ k2, const float4* __restrict__ k3,
    const float4* __restrict__ k4,
    float c0, float c1, float c2, float c3, float c4,
    int nk, int n4)
{
    int i = blockIdx.x * 256 + threadIdx.x;
    if (i >= n4) return;
    float4 r = x0[i];
    if (nk > 0) { float4 a = k0[i]; r.x=fmaf(c0,a.x,r.x); r.y=fmaf(c0,a.y,r.y); r.z=fmaf(c0,a.z,r.z); r.w=fmaf(c0,a.w,r.w); }
    if (nk > 1) { float4 a = k1[i]; r.x=fmaf(c1,a.x,r.x); r.y=fmaf(c1,a.y,r.y); r.z=fmaf(c1,a.z,r.z); r.w=fmaf(c1,a.w,r.w); }
    if (nk > 2) { float4 a = k2[i]; r.x=fmaf(c2,a.x,r.x); r.y=fmaf(c2,a.y,r.y); r.z=fmaf(c2,a.z,r.z); r.w=fmaf(c2,a.w,r.w); }
    if (nk > 3) { float4 a = k3[i]; r.x=fmaf(c3,a.x,r.x); r.y=fmaf(c3,a.y,r.y); r.z=fmaf(c3,a.z,r.z); r.w=fmaf(c3,a.w,r.w); }
    if (nk > 4) { float4 a = k4[i]; r.x=fmaf(c4,a.x,r.x); r.y=fmaf(c4,a.y,r.y); r.z=fmaf(c4,a.z,r.z); r.w=fmaf(c4,a.w,r.w); }
    out[i] = r;
}

// th2 half of hcat: th2 *= (1 - a2^2); a2 = first half
__global__ __launch_bounds__(256) void make_ta2k(float4* __restrict__ hcat, int n4)
{
    int i = blockIdx.x * 256 + threadIdx.x;
    if (i >= n4) return;
    float4 a = hcat[i];
    float4 t = hcat[n4 + i];
    t.x *= (1.f - a.x * a.x);
    t.y *= (1.f - a.y * a.y);
    t.z *= (1.f - a.z * a.z);
    t.w *= (1.f - a.w * a.w);
    hcat[n4 + i] = t;
}

// L[row] += coef * sum_h ta2[row,h] * v[row,h]   (one wave per row, H=512)
__global__ __launch_bounds__(256) void tr_add(
    const float* __restrict__ ta2, const float* __restrict__ v,
    float* __restrict__ L, float coef)
{
    int wave = threadIdx.x >> 6, lane = threadIdx.x & 63;
    int row = blockIdx.x * 4 + wave;
    const float* tp = ta2 + (size_t)row * 512;
    const float* vp = v   + (size_t)row * 512;
    float s = 0.f;
    #pragma unroll
    for (int h = 0; h < 512; h += 64) s = fmaf(tp[h + lane], vp[h + lane], s);
    #pragma unroll
    for (int off = 32; off; off >>= 1) s += __shfl_down(s, off, 64);
    if (lane == 0) L[row] += coef * s;
}

// gc[b,h] = cond[b]*wrow[h] + bias[h]   (energy flow, C=1)
__global__ __launch_bounds__(256) void outer_bias(
    float* __restrict__ gc, const float* __restrict__ cond,
    const float* __restrict__ wrow, const float* __restrict__ bias)
{
    int i = blockIdx.x * 256 + threadIdx.x;
    int b = i >> 9, h = i & 511;
    gc[i] = fmaf(cond[b], wrow[h], bias[h]);
}

// out(CxR) = in(RxC)^T
__global__ __launch_bounds__(256) void transpose_k(
    const float* __restrict__ in, float* __restrict__ out, int R, int Cc)
{
    __shared__ float t[32][33];
    int r0 = blockIdx.y * 32, c0 = blockIdx.x * 32;
    int tx = threadIdx.x & 31, ty = threadIdx.x >> 5;
    for (int i = ty; i < 32; i += 8) {
        int r = r0 + i, c = c0 + tx;
        if (r < R && c < Cc) t[i][tx] = in[(size_t)r * Cc + c];
    }
    __syncthreads();
    for (int i = ty; i < 32; i += 8) {
        int c = c0 + i, r = r0 + tx;
        if (r < R && c < Cc) out[(size_t)c * R + r] = t[tx][i];
    }
}

// acc += sum_b ( -0.5*sum_d z^2 - 0.5*D*log2pi + L[b] )
__global__ __launch_bounds__(256) void final_reduce(
    const float* __restrict__ z, const float* __restrict__ L,
    float* __restrict__ acc, int D)
{
    __shared__ float ps[4];
    int wave = threadIdx.x >> 6, lane = threadIdx.x & 63;
    int row = blockIdx.x * 4 + wave;
    const float* zp = z + (size_t)row * D;
    float s = 0.f;
    for (int d = lane; d < D; d += 64) { float x = zp[d]; s = fmaf(x, x, s); }
    #pragma unroll
    for (int off = 32; off; off >>= 1) s += __shfl_down(s, off, 64);
    if (lane == 0) ps[wave] = -0.5f * s - 0.5f * (float)D * LOG2PI + L[row];
    __syncthreads();
    if (threadIdx.x == 0) atomicAdd(acc, ps[0] + ps[1] + ps[2] + ps[3]);
}

__global__ void finalize_k(float* __restrict__ out, const float* __restrict__ acc)
{
    out[0] = -(acc[0] + acc[1]) * (1.f / 8192.f);
}

// ---------------------------------------------------------------------------
extern "C" void kernel_launch(void* const* d_in, const int* in_sizes, int n_in,
                              void* d_out, int out_size, void* d_ws, size_t ws_size,
                              hipStream_t stream)
{
    (void)in_sizes; (void)n_in; (void)out_size; (void)ws_size;
    const float* voxel  = (const float*)d_in[0];
    const float* energy = (const float*)d_in[1];
    const float* cond   = (const float*)d_in[2];
    const float* eps_v  = (const float*)d_in[3];
    const float* eps_e  = (const float*)d_in[4];
    const float* Wt[2][5] = {
        {(const float*)d_in[5], (const float*)d_in[6], (const float*)d_in[7], (const float*)d_in[8], (const float*)d_in[9]},
        {(const float*)d_in[11],(const float*)d_in[12],(const float*)d_in[13],(const float*)d_in[14],(const float*)d_in[15]}};
    const float* b3t[2] = {(const float*)d_in[10], (const float*)d_in[16]};

    const int Bn = 8192, H = 512;
    const size_t BH = (size_t)Bn * H;
    const size_t BDv = (size_t)Bn * 504;

    char* wp = (char*)d_ws;
    auto alloc = [&](size_t elems) { float* p = (float*)wp; wp += elems * sizeof(float); return p; };
    float* th1  = alloc(BH);
    float* gc   = alloc(BH);
    float* vbuf = alloc(BH);
    float* acat = alloc(2 * BH);   // a1 | ta1
    float* hcat = alloc(2 * BH);   // a2 | ta2   (also temp for W3^T)
    float* kb[5]; for (int i = 0; i < 5; ++i) kb[i] = alloc(BDv);
    float* xi   = alloc(BDv);      // stage input; doubles as k5
    float* xx   = alloc(BDv);
    float* L    = alloc(Bn);
    float* acc  = alloc(8);

    (void)hipMemsetAsync(acc, 0, 2 * sizeof(float), stream);

    static const double AD[6][5] = {
        {0,0,0,0,0},
        {1.0/5,0,0,0,0},
        {3.0/40,9.0/40,0,0,0},
        {44.0/45,-56.0/15,32.0/9,0,0},
        {19372.0/6561,-25360.0/2187,64448.0/6561,-212.0/729,0},
        {9017.0/3168,-355.0/33,46732.0/5247,49.0/176,-5103.0/18656}};
    static const double Bcf[6] = {35.0/384, 0.0, 500.0/1113, 125.0/192, -2187.0/6784, 11.0/84};
    static const double CD[6]  = {0.0, 0.2, 0.3, 0.8, 8.0/9.0, 1.0};
    const double dtd = -0.1;

    auto G = [&](int epi, const float* A, int lda, const float* Bm, int ldb,
                 float* C, int ldc, int M, int N, int K,
                 const float* p0, const float* p1, const float* p2, const float* p3,
                 float sc, float* C2, int halfM) {
        dim3 g((N + TILE - 1) / TILE, M / TILE), blk(256);
        switch (epi) {
        case 0: gemm_k<0><<<g, blk, 0, stream>>>(A,lda,Bm,ldb,C,ldc,M,N,K,p0,p1,p2,p3,sc,C2,halfM); break;
        case 1: gemm_k<1><<<g, blk, 0, stream>>>(A,lda,Bm,ldb,C,ldc,M,N,K,p0,p1,p2,p3,sc,C2,halfM); break;
        case 2: gemm_k<2><<<g, blk, 0, stream>>>(A,lda,Bm,ldb,C,ldc,M,N,K,p0,p1,p2,p3,sc,C2,halfM); break;
        case 3: gemm_k<3><<<g, blk, 0, stream>>>(A,lda,Bm,ldb,C,ldc,M,N,K,p0,p1,p2,p3,sc,C2,halfM); break;
        case 4: gemm_k<4><<<g, blk, 0, stream>>>(A,lda,Bm,ldb,C,ldc,M,N,K,p0,p1,p2,p3,sc,C2,halfM); break;
        }
    };

    for (int flow = 0; flow < 2; ++flow) {
        const int D = (flow == 0) ? 504 : 45;
        const float* x_in = (flow == 0) ? voxel : energy;
        const float* eps  = (flow == 0) ? eps_v : eps_e;
        const float* W1 = Wt[flow][0]; const float* b1 = Wt[flow][1];
        const float* W2 = Wt[flow][2]; const float* b2 = Wt[flow][3];
        const float* W3 = Wt[flow][4]; const float* b3 = b3t[flow];
        const size_t BD = (size_t)Bn * D;
        const int n4 = (int)(BD / 4);
        const int axg = (n4 + 255) / 256;

        (void)hipMemsetAsync(L, 0, Bn * sizeof(float), stream);

        // ---- precompute: TH1 = eps @ W1[:D]
        G(0, eps, D, W1, H, th1, H, Bn, H, D, 0,0,0,0, 0.f, 0, 0);
        // ---- precompute: Gc = cond-part @ W1 + bias
        if (flow == 0) {
            // Gc = energy @ W1v[505:550] + cond*W1v[550] + b1v
            G(4, energy, 45, W1 + (size_t)505 * H, H, gc, H, Bn, H, 45,
              cond, 0, W1 + (size_t)550 * H, b1, 0.f, 0, 0);
        } else {
            outer_bias<<<(int)(BH / 256), 256, 0, stream>>>(gc, cond, W1 + (size_t)46 * H, b1);
        }
        // ---- precompute: V = eps @ W3^T   (transpose W3 into hcat temp first)
        {
            float* w3t = hcat;
            dim3 tg((D + 31) / 32, (H + 31) / 32);
            transpose_k<<<tg, 256, 0, stream>>>(W3, w3t, H, D);
            G(0, eps, D, w3t, H, vbuf, H, Bn, H, D, 0,0,0,0, 0.f, 0, 0);
        }

        const float* cur = x_in;
        for (int s = 0; s < 10; ++s) {
            float t0f = 1.0f + (float)s * -0.1f;
            for (int i = 0; i < 6; ++i) {
                float ti = t0f + (float)(CD[i] * dtd);
                const float* Aptr = cur;
                if (i > 0) {
                    float c[5] = {0,0,0,0,0};
                    for (int j = 0; j < i; ++j) c[j] = (float)(dtd * AD[i][j]);
                    axpy5<<<axg, 256, 0, stream>>>((float4*)xi, (const float4*)cur,
                        (const float4*)kb[0], (const float4*)kb[1], (const float4*)kb[2],
                        (const float4*)kb[3], (const float4*)kb[4],
                        c[0], c[1], c[2], c[3], c[4], i, n4);
                    Aptr = xi;
                }
                // GEMM1: a1/ta1  (fused tanh + tangent epilogue)
                G(1, Aptr, D, W1, H, acat, H, Bn, H, D,
                  gc, th1, W1 + (size_t)D * H, 0, ti, acat + BH, 0);
                // GEMM2: stacked [a1;ta1] @ W2 (stage 1: value path only, b1 coeff = 0)
                int M2 = (i == 1) ? Bn : 2 * Bn;
                G(2, acat, H, W2, H, hcat, H, M2, H, H, 0,0,0, b2, 0.f, 0, Bn);
                if (i != 1)
                    make_ta2k<<<(int)(BH / 4 / 256), 256, 0, stream>>>((float4*)hcat, (int)(BH / 4));
                // GEMM3: dx = a2 @ W3 + b3 -> k_i
                float* kout = (i < 5) ? kb[i] : xi;
                G(3, hcat, H, W3, D, kout, D, Bn, D, H, 0,0,0, b3, 0.f, 0, 0);
                // trace: L += dt*b_i * rowdot(ta2, V)
                if (i != 1)
                    tr_add<<<Bn / 4, 256, 0, stream>>>(hcat + BH, vbuf, L, (float)(dtd * Bcf[i]));
            }
            // xx = cur + dt*(b0 k0 + b2 k2 + b3 k3 + b4 k4 + b5 k5)   (b1 = 0)
            axpy5<<<axg, 256, 0, stream>>>((float4*)xx, (const float4*)cur,
                (const float4*)kb[0], (const float4*)kb[2], (const float4*)kb[3],
                (const float4*)kb[4], (const float4*)xi,
                (float)(dtd * Bcf[0]), (float)(dtd * Bcf[2]), (float)(dtd * Bcf[3]),
                (float)(dtd * Bcf[4]), (float)(dtd * Bcf[5]), 5, n4);
            cur = xx;
        }
        final_reduce<<<Bn / 4, 256, 0, stream>>>(cur, L, acc + flow, D);
    }
    finalize_k<<<1, 1, 0, stream>>>((float*)d_out, acc);
}

// Round 2
// 13780.634 us; speedup vs baseline: 4.0693x; 4.0693x over previous
//
#include <hip/hip_runtime.h>
#include <math.h>
#include <stdint.h>

#define LOG2PI 1.8378770664093453f
#define TILE 128
#define BKK 8

typedef __attribute__((ext_vector_type(8))) short bf8;   // 8 bf16 (4 VGPRs)
typedef __attribute__((ext_vector_type(4))) float f4;

__device__ __forceinline__ short f2bf(float f) {
    uint32_t u = __float_as_uint(f);
    u += 0x7fffu + ((u >> 16) & 1u);          // RNE
    return (short)(u >> 16);
}
__device__ __forceinline__ float bf2f(unsigned short u) {
    return __uint_as_float(((uint32_t)u) << 16);
}
__device__ __forceinline__ void gload16(const void* g, void* l) {
    __builtin_amdgcn_global_load_lds(
        (const __attribute__((address_space(1))) uint32_t*)(uintptr_t)g,
        (__attribute__((address_space(3))) uint32_t*)(uintptr_t)l, 16, 0, 0);
}

// ---------------------------------------------------------------------------
// bf16 MFMA GEMM: C(M x Nc) = A(M x K) @ Bt(N x K)^T ; A,Bt bf16 row-major,
// K % 64 == 0, M % 128 == 0. 128x128 tile, BK=64, 4 waves, 64x64 per wave.
// EPI 1 (layer1): a1 = tanh(acc + sc0*p2[n] + p0[idx]); Cb=bf16(a1);
//                 Cb2 = bf16((1-a1^2)*p1[idx])
// EPI 2 (layer2): rows<halfM: a=tanh(acc+p3[n]) -> Cb=bf16(a)
//                 rows>=halfM: C[(m-halfM)*ldc+n] = acc      (tangent, no bias)
// EPI 3 (layer3): C = acc + p3[n]
// ---------------------------------------------------------------------------
template<int EPI>
__global__ __launch_bounds__(256) void mgemm(
    const short* __restrict__ A, const short* __restrict__ Bt, int K,
    float* __restrict__ C, int ldc, int Nc,
    const float* __restrict__ p0, const float* __restrict__ p1,
    const float* __restrict__ p2, const float* __restrict__ p3,
    float sc0, short* __restrict__ Cb, short* __restrict__ Cb2, int halfM)
{
    __shared__ char lds[32768];                 // A tile 16KB | B tile 16KB
    const int tid = threadIdx.x, wave = tid >> 6, lane = tid & 63;
    const int m0 = blockIdx.y * 128, n0 = blockIdx.x * 128;
    const int wr = wave >> 1, wc = wave & 1;

    f4 acc[4][4];
    #pragma unroll
    for (int m = 0; m < 4; ++m)
        #pragma unroll
        for (int n = 0; n < 4; ++n) acc[m][n] = (f4)0.0f;

    // staging: issue q writes rows q*8..q*8+7, lane l -> LDS linear q*1024+l*16
    // source col pre-swizzled: cb_src = cb_lds ^ ((row&7)<<4); row&7 == lane>>3
    const int cbs  = (((lane & 7) ^ (lane >> 3)) << 4);  // swizzled source byte
    const int lrow = lane >> 3;

    for (int k0 = 0; k0 < K; k0 += 64) {
        __syncthreads();
        #pragma unroll
        for (int i = 0; i < 4; ++i) {
            int q = wave * 4 + i;
            int row = q * 8 + lrow;
            const char* ga = (const char*)(A  + (size_t)(m0 + row) * K + k0) + cbs;
            gload16(ga, lds + q * 1024);
            const char* gb = (const char*)(Bt + (size_t)(n0 + row) * K + k0) + cbs;
            gload16(gb, lds + 16384 + q * 1024);
        }
        __syncthreads();
        #pragma unroll
        for (int kk = 0; kk < 2; ++kk) {
            bf8 af[4], bfr[4];
            #pragma unroll
            for (int m = 0; m < 4; ++m) {
                int row = wr * 64 + m * 16 + (lane & 15);
                int cb  = (((lane >> 4) << 4) + (kk << 6)) ^ ((row & 7) << 4);
                af[m] = *(const bf8*)(lds + row * 128 + cb);
            }
            #pragma unroll
            for (int n = 0; n < 4; ++n) {
                int row = wc * 64 + n * 16 + (lane & 15);
                int cb  = (((lane >> 4) << 4) + (kk << 6)) ^ ((row & 7) << 4);
                bfr[n] = *(const bf8*)(lds + 16384 + row * 128 + cb);
            }
            #pragma unroll
            for (int m = 0; m < 4; ++m)
                #pragma unroll
                for (int n = 0; n < 4; ++n)
                    acc[m][n] = __builtin_amdgcn_mfma_f32_16x16x32_bf16(
                        af[m], bfr[n], acc[m][n], 0, 0, 0);
        }
    }

    #pragma unroll
    for (int m = 0; m < 4; ++m) {
        #pragma unroll
        for (int r = 0; r < 4; ++r) {
            int grow = m0 + wr * 64 + m * 16 + (lane >> 4) * 4 + r;
            #pragma unroll
            for (int n = 0; n < 4; ++n) {
                int gcol = n0 + wc * 64 + n * 16 + (lane & 15);
                if (gcol >= Nc) continue;
                size_t idx = (size_t)grow * ldc + gcol;
                float v = acc[m][n][r];
                if constexpr (EPI == 1) {
                    float a = tanhf(v + sc0 * p2[gcol] + p0[idx]);
                    Cb[idx]  = f2bf(a);
                    Cb2[idx] = f2bf((1.f - a * a) * p1[idx]);
                } else if constexpr (EPI == 2) {
                    if (grow < halfM) {
                        float a = tanhf(v + p3[gcol]);
                        Cb[idx] = f2bf(a);
                    } else {
                        C[(size_t)(grow - halfM) * ldc + gcol] = v;
                    }
                } else if constexpr (EPI == 3) {
                    C[idx] = v + p3[gcol];
                }
            }
        }
    }
}

// ---------------------------------------------------------------------------
// fp32 tiled GEMM (precomputes only). EPI 0: store. EPI 4: + p0[m]*p2[n] + p3[n]
// ---------------------------------------------------------------------------
template<int EPI>
__global__ __launch_bounds__(256) void gemm_k(
    const float* __restrict__ A, int lda,
    const float* __restrict__ Bm, int ldb,
    float* __restrict__ C, int ldc,
    int M, int N, int K,
    const float* __restrict__ p0, const float* __restrict__ p2,
    const float* __restrict__ p3)
{
    __shared__ float As[BKK][TILE];
    __shared__ float Bs[BKK][TILE];
    const int tid = threadIdx.x;
    const int tx = tid & 15, ty = tid >> 4;
    const int m0 = blockIdx.y * TILE, n0 = blockIdx.x * TILE;

    float acc[8][8];
    #pragma unroll
    for (int i = 0; i < 8; ++i)
        #pragma unroll
        for (int j = 0; j < 8; ++j) acc[i][j] = 0.f;

    const int arow = tid >> 1;
    const int ak0  = (tid & 1) * 4;
    const int bkr  = tid >> 5;
    const int bcol = (tid & 31) * 4;
    const float* Arow = A + (size_t)(m0 + arow) * lda;

    for (int k0 = 0; k0 < K; k0 += BKK) {
        #pragma unroll
        for (int j = 0; j < 4; ++j) {
            int k = k0 + ak0 + j;
            As[ak0 + j][arow] = (k < K) ? Arow[k] : 0.f;
        }
        {
            int kb = k0 + bkr;
            const float* Brow = Bm + (size_t)kb * ldb + n0;
            #pragma unroll
            for (int j = 0; j < 4; ++j) {
                int n = n0 + bcol + j;
                Bs[bkr][bcol + j] = (kb < K && n < N) ? Brow[bcol + j] : 0.f;
            }
        }
        __syncthreads();
        #pragma unroll
        for (int kk = 0; kk < BKK; ++kk) {
            float4 a0 = *(const float4*)&As[kk][ty * 8];
            float4 a1 = *(const float4*)&As[kk][ty * 8 + 4];
            float4 b0 = *(const float4*)&Bs[kk][tx * 8];
            float4 b1 = *(const float4*)&Bs[kk][tx * 8 + 4];
            float ar[8] = {a0.x,a0.y,a0.z,a0.w,a1.x,a1.y,a1.z,a1.w};
            float br[8] = {b0.x,b0.y,b0.z,b0.w,b1.x,b1.y,b1.z,b1.w};
            #pragma unroll
            for (int i = 0; i < 8; ++i)
                #pragma unroll
                for (int j = 0; j < 8; ++j)
                    acc[i][j] = fmaf(ar[i], br[j], acc[i][j]);
        }
        __syncthreads();
    }

    #pragma unroll
    for (int i = 0; i < 8; ++i) {
        size_t m = (size_t)m0 + ty * 8 + i;
        #pragma unroll
        for (int j = 0; j < 8; ++j) {
            int n = n0 + tx * 8 + j;
            if (n >= N) continue;
            size_t idx = m * (size_t)ldc + n;
            float v = acc[i][j];
            if constexpr (EPI == 0) C[idx] = v;
            else                    C[idx] = v + p0[m] * p2[n] + p3[n];
        }
    }
}

// out = x0 + sum c_j k_j ; writes f32 (optional) + bf16
__global__ __launch_bounds__(256) void axpy5(
    float4* __restrict__ outf, short* __restrict__ outb,
    const float4* __restrict__ x0,
    const float4* __restrict__ k0, const float4* __restrict__ k1,
    const float4* __restrict__ k2, const float4* __restrict__ k3,
    const float4* __restrict__ k4,
    float c0, float c1, float c2, float c3, float c4,
    int nk, int n4)
{
    int i = blockIdx.x * 256 + threadIdx.x;
    if (i >= n4) return;
    float4 r = x0[i];
    if (nk > 0) { float4 a = k0[i]; r.x=fmaf(c0,a.x,r.x); r.y=fmaf(c0,a.y,r.y); r.z=fmaf(c0,a.z,r.z); r.w=fmaf(c0,a.w,r.w); }
    if (nk > 1) { float4 a = k1[i]; r.x=fmaf(c1,a.x,r.x); r.y=fmaf(c1,a.y,r.y); r.z=fmaf(c1,a.z,r.z); r.w=fmaf(c1,a.w,r.w); }
    if (nk > 2) { float4 a = k2[i]; r.x=fmaf(c2,a.x,r.x); r.y=fmaf(c2,a.y,r.y); r.z=fmaf(c2,a.z,r.z); r.w=fmaf(c2,a.w,r.w); }
    if (nk > 3) { float4 a = k3[i]; r.x=fmaf(c3,a.x,r.x); r.y=fmaf(c3,a.y,r.y); r.z=fmaf(c3,a.z,r.z); r.w=fmaf(c3,a.w,r.w); }
    if (nk > 4) { float4 a = k4[i]; r.x=fmaf(c4,a.x,r.x); r.y=fmaf(c4,a.y,r.y); r.z=fmaf(c4,a.z,r.z); r.w=fmaf(c4,a.w,r.w); }
    if (outf) outf[i] = r;
    short4 h; h.x = f2bf(r.x); h.y = f2bf(r.y); h.z = f2bf(r.z); h.w = f2bf(r.w);
    ((short4*)outb)[i] = h;
}

// L[row] += coef * sum_h (1-a2^2)*th2*v
__global__ __launch_bounds__(256) void tr_add(
    const unsigned short* __restrict__ a2, const float* __restrict__ th2,
    const float* __restrict__ v, float* __restrict__ L, float coef)
{
    int wave = threadIdx.x >> 6, lane = threadIdx.x & 63;
    int row = blockIdx.x * 4 + wave;
    const unsigned short* ap = a2 + (size_t)row * 512;
    const float* tp = th2 + (size_t)row * 512;
    const float* vp = v   + (size_t)row * 512;
    float s = 0.f;
    #pragma unroll
    for (int h = 0; h < 512; h += 64) {
        float a = bf2f(ap[h + lane]);
        s = fmaf((1.f - a * a) * tp[h + lane], vp[h + lane], s);
    }
    #pragma unroll
    for (int off = 32; off; off >>= 1) s += __shfl_down(s, off, 64);
    if (lane == 0) L[row] += coef * s;
}

__global__ __launch_bounds__(256) void outer_bias(
    float* __restrict__ gc, const float* __restrict__ cond,
    const float* __restrict__ wrow, const float* __restrict__ bias)
{
    int i = blockIdx.x * 256 + threadIdx.x;
    int b = i >> 9, h = i & 511;
    gc[i] = fmaf(cond[b], wrow[h], bias[h]);
}

__global__ __launch_bounds__(256) void transpose_k(
    const float* __restrict__ in, float* __restrict__ out, int R, int Cc)
{
    __shared__ float t[32][33];
    int r0 = blockIdx.y * 32, c0 = blockIdx.x * 32;
    int tx = threadIdx.x & 31, ty = threadIdx.x >> 5;
    for (int i = ty; i < 32; i += 8) {
        int r = r0 + i, c = c0 + tx;
        if (r < R && c < Cc) t[i][tx] = in[(size_t)r * Cc + c];
    }
    __syncthreads();
    for (int i = ty; i < 32; i += 8) {
        int c = c0 + i, r = r0 + tx;
        if (r < R && c < Cc) out[(size_t)c * R + r] = t[tx][i];
    }
}

// Bt[n][k] = bf16(in[k][n]) with zero pad (n rows -> Nalloc, k -> Kpad)
__global__ __launch_bounds__(256) void convtrans(
    short* __restrict__ out, const float* __restrict__ in,
    int K, int N, int Kpad, int total)
{
    int i = blockIdx.x * 256 + threadIdx.x;
    if (i >= total) return;
    int n = i / Kpad, k = i - n * Kpad;
    out[i] = (k < K && n < N) ? f2bf(in[(size_t)k * N + n]) : (short)0;
}

__global__ __launch_bounds__(256) void padconv(
    float* __restrict__ outf, short* __restrict__ outb,
    const float* __restrict__ in, int D, int Dpad, int total)
{
    int i = blockIdx.x * 256 + threadIdx.x;
    if (i >= total) return;
    int b = i / Dpad, d = i - b * Dpad;
    float v = (d < D) ? in[(size_t)b * D + d] : 0.f;
    outf[i] = v; outb[i] = f2bf(v);
}

__global__ __launch_bounds__(256) void padvec(
    float* __restrict__ out, const float* __restrict__ in, int N, int Npad)
{
    int i = blockIdx.x * 256 + threadIdx.x;
    if (i < Npad) out[i] = (i < N) ? in[i] : 0.f;
}

__global__ __launch_bounds__(256) void final_reduce(
    const float* __restrict__ z, const float* __restrict__ L,
    float* __restrict__ acc, int Dpad, int Dtrue)
{
    __shared__ float ps[4];
    int wave = threadIdx.x >> 6, lane = threadIdx.x & 63;
    int row = blockIdx.x * 4 + wave;
    const float* zp = z + (size_t)row * Dpad;
    float s = 0.f;
    for (int d = lane; d < Dpad; d += 64) { float x = zp[d]; s = fmaf(x, x, s); }
    #pragma unroll
    for (int off = 32; off; off >>= 1) s += __shfl_down(s, off, 64);
    if (lane == 0) ps[wave] = -0.5f * s - 0.5f * (float)Dtrue * LOG2PI + L[row];
    __syncthreads();
    if (threadIdx.x == 0) atomicAdd(acc, ps[0] + ps[1] + ps[2] + ps[3]);
}

__global__ void finalize_k(float* __restrict__ out, const float* __restrict__ acc)
{
    out[0] = -(acc[0] + acc[1]) * (1.f / 8192.f);
}

// ---------------------------------------------------------------------------
extern "C" void kernel_launch(void* const* d_in, const int* in_sizes, int n_in,
                              void* d_out, int out_size, void* d_ws, size_t ws_size,
                              hipStream_t stream)
{
    (void)in_sizes; (void)n_in; (void)out_size; (void)ws_size;
    const float* voxel  = (const float*)d_in[0];
    const float* energy = (const float*)d_in[1];
    const float* cond   = (const float*)d_in[2];
    const float* eps_v  = (const float*)d_in[3];
    const float* eps_e  = (const float*)d_in[4];
    const float* Wt[2][5] = {
        {(const float*)d_in[5], (const float*)d_in[6], (const float*)d_in[7], (const float*)d_in[8], (const float*)d_in[9]},
        {(const float*)d_in[11],(const float*)d_in[12],(const float*)d_in[13],(const float*)d_in[14],(const float*)d_in[15]}};
    const float* b3t[2] = {(const float*)d_in[10], (const float*)d_in[16]};

    const int Bn = 8192, H = 512;
    const size_t BH = (size_t)Bn * H;

    char* wp = (char*)d_ws;
    auto alloc = [&](size_t bytes) { char* p = wp; wp += (bytes + 255) & ~(size_t)255; return p; };
    float* th1   = (float*)alloc(BH * 4);
    float* gc    = (float*)alloc(BH * 4);
    float* vbuf  = (float*)alloc(BH * 4);
    short* acat  = (short*)alloc(2 * BH * 2);   // a1 | ta1 (bf16)
    float* th2f  = (float*)alloc(BH * 4);       // tangent layer-2 (f32); W3^T temp
    short* a2bf  = (short*)alloc(BH * 2);
    short* w1t   = (short*)alloc((size_t)512 * 512 * 2);
    short* w2t   = (short*)alloc((size_t)512 * 512 * 2);
    short* w3t   = (short*)alloc((size_t)512 * 512 * 2);
    float* b3pad = (float*)alloc(512 * 4);
    float* xf0   = (float*)alloc(BH * 4);
    float* xf1   = (float*)alloc(BH * 4);
    short* xb    = (short*)alloc(BH * 2);       // bf16 of current state
    short* xib   = (short*)alloc(BH * 2);       // bf16 stage input
    float* kb[5]; for (int i = 0; i < 5; ++i) kb[i] = (float*)alloc(BH * 4);
    float* L     = (float*)alloc(Bn * 4);
    float* acc   = (float*)alloc(256);

    (void)hipMemsetAsync(acc, 0, 2 * sizeof(float), stream);

    static const double AD[6][5] = {
        {0,0,0,0,0},
        {1.0/5,0,0,0,0},
        {3.0/40,9.0/40,0,0,0},
        {44.0/45,-56.0/15,32.0/9,0,0},
        {19372.0/6561,-25360.0/2187,64448.0/6561,-212.0/729,0},
        {9017.0/3168,-355.0/33,46732.0/5247,49.0/176,-5103.0/18656}};
    static const double Bcf[6] = {35.0/384, 0.0, 500.0/1113, 125.0/192, -2187.0/6784, 11.0/84};
    static const double CD[6]  = {0.0, 0.2, 0.3, 0.8, 8.0/9.0, 1.0};
    const double dtd = -0.1;

    for (int flow = 0; flow < 2; ++flow) {
        const int D    = (flow == 0) ? 504 : 45;
        const int Dpad = (flow == 0) ? 512 : 64;
        const float* x_in = (flow == 0) ? voxel : energy;
        const float* eps  = (flow == 0) ? eps_v : eps_e;
        const float* W1 = Wt[flow][0]; const float* b1 = Wt[flow][1];
        const float* W2 = Wt[flow][2]; const float* b2 = Wt[flow][3];
        const float* W3 = Wt[flow][4]; const float* b3 = b3t[flow];
        const int n4  = Bn * Dpad / 4;
        const int axg = (n4 + 255) / 256;

        (void)hipMemsetAsync(L, 0, Bn * sizeof(float), stream);

        // ---- weight prep (bf16, transposed [N][Kpad], zero-padded)
        convtrans<<<(512 * Dpad + 255) / 256, 256, 0, stream>>>(w1t, W1, D, 512, Dpad, 512 * Dpad);
        convtrans<<<(512 * 512 + 255) / 256, 256, 0, stream>>>(w2t, W2, 512, 512, 512, 512 * 512);
        convtrans<<<(512 * 512 + 255) / 256, 256, 0, stream>>>(w3t, W3, 512, D, 512, 512 * 512);
        padvec<<<2, 256, 0, stream>>>(b3pad, b3, D, Dpad);
        padconv<<<(Bn * Dpad + 255) / 256, 256, 0, stream>>>(xf0, xb, x_in, D, Dpad, Bn * Dpad);

        // ---- fp32 precomputes: th1 = eps @ W1[:D]; gc; V = eps @ W3^T
        gemm_k<0><<<dim3(4, 64), 256, 0, stream>>>(eps, D, W1, H, th1, H, Bn, H, D, 0, 0, 0);
        if (flow == 0) {
            gemm_k<4><<<dim3(4, 64), 256, 0, stream>>>(energy, 45, W1 + (size_t)505 * H, H,
                gc, H, Bn, H, 45, cond, W1 + (size_t)550 * H, b1);
        } else {
            outer_bias<<<(int)(BH / 256), 256, 0, stream>>>(gc, cond, W1 + (size_t)46 * H, b1);
        }
        {
            float* w3tf = th2f;   // temp
            dim3 tg((D + 31) / 32, (H + 31) / 32);
            transpose_k<<<tg, 256, 0, stream>>>(W3, w3tf, H, D);
            gemm_k<0><<<dim3(4, 64), 256, 0, stream>>>(eps, D, w3tf, H, vbuf, H, Bn, H, D, 0, 0, 0);
        }

        const float* p2row = W1 + (size_t)D * H;   // t-row of W1
        float* curf = xf0;
        for (int s = 0; s < 10; ++s) {
            float t0f = 1.0f + (float)s * -0.1f;
            for (int i = 0; i < 6; ++i) {
                float ti = t0f + (float)(CD[i] * dtd);
                const short* Abf = xb;
                if (i > 0) {
                    float c[5] = {0,0,0,0,0};
                    for (int j = 0; j < i; ++j) c[j] = (float)(dtd * AD[i][j]);
                    axpy5<<<axg, 256, 0, stream>>>(nullptr, xib, (const float4*)curf,
                        (const float4*)kb[0], (const float4*)kb[1], (const float4*)kb[2],
                        (const float4*)kb[3], (const float4*)kb[4],
                        c[0], c[1], c[2], c[3], c[4], i, n4);
                    Abf = xib;
                }
                // layer 1: a1/ta1 (bf16 out)
                mgemm<1><<<dim3(4, 64), 256, 0, stream>>>(Abf, w1t, Dpad,
                    nullptr, 512, 512, gc, th1, p2row, nullptr, ti, acat, acat + BH, 0);
                // layer 2: stacked [a1;ta1] @ W2   (stage i==1: value rows only)
                int M2 = (i == 1) ? Bn : 2 * Bn;
                mgemm<2><<<dim3(4, M2 / 128), 256, 0, stream>>>(acat, w2t, 512,
                    th2f, 512, 512, nullptr, nullptr, nullptr, b2, 0.f, a2bf, nullptr, Bn);
                // layer 3: k_i = a2 @ W3 + b3  (k5 reuses kb[1]; b1==0)
                float* kout = (i < 5) ? kb[i] : kb[1];
                mgemm<3><<<dim3((Dpad + 127) / 128, 64), 256, 0, stream>>>(a2bf, w3t, 512,
                    kout, Dpad, Dpad, nullptr, nullptr, nullptr, b3pad, 0.f, nullptr, nullptr, 0);
                if (i != 1)
                    tr_add<<<Bn / 4, 256, 0, stream>>>((const unsigned short*)a2bf, th2f,
                        vbuf, L, (float)(dtd * Bcf[i]));
            }
            float* nxt = (curf == xf0) ? xf1 : xf0;
            axpy5<<<axg, 256, 0, stream>>>((float4*)nxt, xb, (const float4*)curf,
                (const float4*)kb[0], (const float4*)kb[2], (const float4*)kb[3],
                (const float4*)kb[4], (const float4*)kb[1],
                (float)(dtd * Bcf[0]), (float)(dtd * Bcf[2]), (float)(dtd * Bcf[3]),
                (float)(dtd * Bcf[4]), (float)(dtd * Bcf[5]), 5, n4);
            curf = nxt;
        }
        final_reduce<<<Bn / 4, 256, 0, stream>>>(curf, L, acc + flow, Dpad, D);
    }
    finalize_k<<<1, 1, 0, stream>>>((float*)d_out, acc);
}

// Round 4
// 12012.068 us; speedup vs baseline: 4.6684x; 1.1472x over previous
//
#include <hip/hip_runtime.h>
#include <math.h>
#include <stdint.h>

#define LOG2PI 1.8378770664093453f
#define TILE 128
#define BKK 8

typedef __attribute__((ext_vector_type(8))) short bf8;   // 8 bf16 (4 VGPRs)
typedef __attribute__((ext_vector_type(4))) float f4;

__device__ __forceinline__ short f2bf(float f) {
    uint32_t u = __float_as_uint(f);
    u += 0x7fffu + ((u >> 16) & 1u);          // RNE
    return (short)(u >> 16);
}
__device__ __forceinline__ void gload16(const void* g, void* l) {
    __builtin_amdgcn_global_load_lds(
        (const __attribute__((address_space(1))) uint32_t*)(uintptr_t)g,
        (__attribute__((address_space(3))) uint32_t*)(uintptr_t)l, 16, 0, 0);
}
__device__ __forceinline__ float4 ax4(float4 p, float4 a, float c) {
    p.x = fmaf(c, a.x, p.x); p.y = fmaf(c, a.y, p.y);
    p.z = fmaf(c, a.z, p.z); p.w = fmaf(c, a.w, p.w);
    return p;
}

// ---------------------------------------------------------------------------
// Fused FFJORD stage kernel. 256 blocks x 32 rows. H = 512.
// Phase B: pre1 = Pcur + sum c_j P_j + ti*wt + gc; a1 = tanh(pre1) -> LDS;
//          ta1 = (1-a1^2)*th1 -> LDS  (stacked rows 32..63)
// Phase C: [a1;ta1] @ W2 (K=512). val rows -> a2 = tanh(+b2) -> LDS (overlay);
//          tan rows -> ta2 = (1-a2^2)*tan (regs); trace += ta2 . vbuf -> L
// Phase D: a2 @ [W3 | W31] (N = DPAD+512):
//          cols < DPAD  -> xf += kcoef*(acc+b3)      (x-update fused; b1==0 -> skip)
//          cols >= DPAD -> Pout = acc + b31          (P_i for later stages)
// ---------------------------------------------------------------------------
template<int DPAD>
__global__ __launch_bounds__(256, 1) void stage_k(
    const float* __restrict__ Pcur,
    const float* __restrict__ P0, const float* __restrict__ P1,
    const float* __restrict__ P2, const float* __restrict__ P3,
    const float* __restrict__ P4,
    float c0, float c1, float c2, float c3, float c4, int nk,
    const float* __restrict__ gc, const float* __restrict__ th1,
    const float* __restrict__ vbuf, const float* __restrict__ wt,
    const float* __restrict__ b2, const float* __restrict__ b3p,
    const float* __restrict__ b31,
    const short* __restrict__ w2t, const short* __restrict__ w3c,
    float* __restrict__ xf, float* __restrict__ Pout,
    float* __restrict__ L, float ti, float tcoef, float kcoef)
{
    __shared__ char lds[65536];   // [64 rows][512 bf16] a1|ta1; a2 overlays rows 0-31
    const int tid = threadIdx.x, wave = tid >> 6, lane = tid & 63;
    const int m0 = blockIdx.x * 32;

    // ---------------- Phase B ----------------
    #pragma unroll
    for (int it = 0; it < 16; ++it) {
        int e = (it << 8) + tid;
        int row = e >> 7, cc = e & 127;
        size_t gi = ((size_t)(m0 + row) << 7) + cc;
        float4 p = ((const float4*)Pcur)[gi];
        if (nk > 0) p = ax4(p, ((const float4*)P0)[gi], c0);
        if (nk > 1) p = ax4(p, ((const float4*)P1)[gi], c1);
        if (nk > 2) p = ax4(p, ((const float4*)P2)[gi], c2);
        if (nk > 3) p = ax4(p, ((const float4*)P3)[gi], c3);
        if (nk > 4) p = ax4(p, ((const float4*)P4)[gi], c4);
        float4 w = ((const float4*)wt)[cc];
        float4 g = ((const float4*)gc)[gi];
        float4 t = ((const float4*)th1)[gi];
        float ax = tanhf(fmaf(ti, w.x, p.x) + g.x);
        float ay = tanhf(fmaf(ti, w.y, p.y) + g.y);
        float az = tanhf(fmaf(ti, w.z, p.z) + g.z);
        float aw = tanhf(fmaf(ti, w.w, p.w) + g.w);
        short4 s1; s1.x = f2bf(ax); s1.y = f2bf(ay); s1.z = f2bf(az); s1.w = f2bf(aw);
        short4 s2; s2.x = f2bf((1.f - ax * ax) * t.x);
        s2.y = f2bf((1.f - ay * ay) * t.y);
        s2.z = f2bf((1.f - az * az) * t.z);
        s2.w = f2bf((1.f - aw * aw) * t.w);
        int base = (row << 10) + ((cc << 3) ^ ((row & 7) << 4));
        *(short4*)(lds + base) = s1;
        *(short4*)(lds + 32768 + base) = s2;
    }
    __syncthreads();

    // ---------------- Phase C: stacked GEMM M=64, N=128/wave, K=512 --------
    f4 acc[4][8];
    #pragma unroll
    for (int mt = 0; mt < 4; ++mt)
        #pragma unroll
        for (int nt = 0; nt < 8; ++nt) acc[mt][nt] = (f4)0.0f;

    {
        const short* wb = w2t + ((size_t)(wave * 128 + (lane & 15)) << 9) + ((lane >> 4) << 3);
        bf8 bcur[8], bnxt[8];
        #pragma unroll
        for (int nt = 0; nt < 8; ++nt) bcur[nt] = *(const bf8*)(wb + ((size_t)nt << 13));
        for (int kt = 0; kt < 16; ++kt) {
            bf8 af[4];
            int kb = (kt << 6) + ((lane >> 4) << 4);
            #pragma unroll
            for (int mt = 0; mt < 4; ++mt) {
                int row = mt * 16 + (lane & 15);
                af[mt] = *(const bf8*)(lds + (row << 10) + (kb ^ ((row & 7) << 4)));
            }
            if (kt < 15) {
                #pragma unroll
                for (int nt = 0; nt < 8; ++nt)
                    bnxt[nt] = *(const bf8*)(wb + ((size_t)nt << 13) + (kt + 1) * 32);
            }
            #pragma unroll
            for (int mt = 0; mt < 4; ++mt)
                #pragma unroll
                for (int nt = 0; nt < 8; ++nt)
                    acc[mt][nt] = __builtin_amdgcn_mfma_f32_16x16x32_bf16(
                        af[mt], bcur[nt], acc[mt][nt], 0, 0, 0);
            #pragma unroll
            for (int nt = 0; nt < 8; ++nt) bcur[nt] = bnxt[nt];
        }
    }
    __syncthreads();   // all a1/ta1 reads done before a2 overlay

    // ---------------- Phase C epilogue: a2 -> LDS, trace -> L --------------
    float trp[2][4] = {{0.f,0.f,0.f,0.f},{0.f,0.f,0.f,0.f}};
    #pragma unroll
    for (int mt = 0; mt < 2; ++mt) {
        #pragma unroll
        for (int nt = 0; nt < 8; ++nt) {
            int col = wave * 128 + nt * 16 + (lane & 15);
            float bb = b2[col];
            #pragma unroll
            for (int r = 0; r < 4; ++r) {
                int row = mt * 16 + ((lane >> 4) << 2) + r;
                float a = tanhf(acc[mt][nt][r] + bb);
                *(short*)(lds + (row << 10) + ((col << 1) ^ ((row & 7) << 4))) = f2bf(a);
                float ta2 = (1.f - a * a) * acc[mt + 2][nt][r];
                trp[mt][r] = fmaf(ta2, vbuf[((size_t)(m0 + row) << 9) + col], trp[mt][r]);
            }
        }
    }
    #pragma unroll
    for (int mt = 0; mt < 2; ++mt)
        #pragma unroll
        for (int r = 0; r < 4; ++r) {
            float s = trp[mt][r];
            s += __shfl_xor(s, 1); s += __shfl_xor(s, 2);
            s += __shfl_xor(s, 4); s += __shfl_xor(s, 8);
            trp[mt][r] = s;
        }
    if ((lane & 15) == 0) {
        #pragma unroll
        for (int mt = 0; mt < 2; ++mt)
            #pragma unroll
            for (int r = 0; r < 4; ++r) {
                int row = mt * 16 + ((lane >> 4) << 2) + r;
                atomicAdd(&L[m0 + row], tcoef * trp[mt][r]);
            }
    }
    __syncthreads();   // a2 visible

    // ---------------- Phase D: a2 @ [W3|W31], N = DPAD+512 ----------------
    constexpr int NTOT = DPAD + 512;
    constexpr int NW = NTOT / 4;     // cols per wave
    constexpr int NTW = NW / 16;     // 16-col tiles per wave
    for (int cb = 0; cb < NTW; cb += 8) {
        const int NT = (NTW - cb < 8) ? (NTW - cb) : 8;
        f4 acc2[2][8];
        #pragma unroll
        for (int mt = 0; mt < 2; ++mt)
            #pragma unroll
            for (int nt = 0; nt < 8; ++nt) acc2[mt][nt] = (f4)0.0f;

        const short* wb3 = w3c + ((size_t)(wave * NW + cb * 16 + (lane & 15)) << 9) + ((lane >> 4) << 3);
        bf8 bcur[8], bnxt[8];
        #pragma unroll
        for (int nt = 0; nt < 8; ++nt)
            if (nt < NT) bcur[nt] = *(const bf8*)(wb3 + ((size_t)nt << 13));
        for (int kt = 0; kt < 16; ++kt) {
            bf8 af[2];
            int kb = (kt << 6) + ((lane >> 4) << 4);
            #pragma unroll
            for (int mt = 0; mt < 2; ++mt) {
                int row = mt * 16 + (lane & 15);
                af[mt] = *(const bf8*)(lds + (row << 10) + (kb ^ ((row & 7) << 4)));
            }
            if (kt < 15) {
                #pragma unroll
                for (int nt = 0; nt < 8; ++nt)
                    if (nt < NT) bnxt[nt] = *(const bf8*)(wb3 + ((size_t)nt << 13) + (kt + 1) * 32);
            }
            #pragma unroll
            for (int mt = 0; mt < 2; ++mt)
                #pragma unroll
                for (int nt = 0; nt < 8; ++nt)
                    if (nt < NT)
                        acc2[mt][nt] = __builtin_amdgcn_mfma_f32_16x16x32_bf16(
                            af[mt], bcur[nt], acc2[mt][nt], 0, 0, 0);
            #pragma unroll
            for (int nt = 0; nt < 8; ++nt)
                if (nt < NT) bcur[nt] = bnxt[nt];
        }
        #pragma unroll
        for (int mt = 0; mt < 2; ++mt) {
            #pragma unroll
            for (int nt = 0; nt < 8; ++nt) {
                if (nt >= NT) continue;
                int col = wave * NW + (cb + nt) * 16 + (lane & 15);
                #pragma unroll
                for (int r = 0; r < 4; ++r) {
                    int row = mt * 16 + ((lane >> 4) << 2) + r;
                    size_t grow = (size_t)(m0 + row);
                    float v = acc2[mt][nt][r];
                    if (col < DPAD) {
                        if (kcoef != 0.f) {
                            size_t xi = grow * DPAD + col;
                            xf[xi] = fmaf(kcoef, v + b3p[col], xf[xi]);
                        }
                    } else {
                        Pout[(grow << 9) + (col - DPAD)] = v + b31[col - DPAD];
                    }
                }
            }
        }
    }
}

// ---------------------------------------------------------------------------
// bf16 MFMA GEMM (precomputes): C(M x 512) f32 = A(M x K)bf16 @ Bt(512 x K)^T
// K % 64 == 0, M % 128 == 0. 128x128 tile, BK=64, 4 waves.
// ---------------------------------------------------------------------------
__global__ __launch_bounds__(256) void mgemm0(
    const short* __restrict__ A, const short* __restrict__ Bt, int K,
    float* __restrict__ C)
{
    __shared__ char lds[32768];
    const int tid = threadIdx.x, wave = tid >> 6, lane = tid & 63;
    const int m0 = blockIdx.y * 128, n0 = blockIdx.x * 128;
    const int wr = wave >> 1, wc = wave & 1;

    f4 acc[4][4];
    #pragma unroll
    for (int m = 0; m < 4; ++m)
        #pragma unroll
        for (int n = 0; n < 4; ++n) acc[m][n] = (f4)0.0f;

    const int cbs  = (((lane & 7) ^ (lane >> 3)) << 4);
    const int lrow = lane >> 3;

    for (int k0 = 0; k0 < K; k0 += 64) {
        __syncthreads();
        #pragma unroll
        for (int i = 0; i < 4; ++i) {
            int q = wave * 4 + i;
            int row = q * 8 + lrow;
            gload16((const char*)(A  + (size_t)(m0 + row) * K + k0) + cbs, lds + q * 1024);
            gload16((const char*)(Bt + (size_t)(n0 + row) * K + k0) + cbs, lds + 16384 + q * 1024);
        }
        __syncthreads();
        #pragma unroll
        for (int kk = 0; kk < 2; ++kk) {
            bf8 af[4], bfr[4];
            #pragma unroll
            for (int m = 0; m < 4; ++m) {
                int row = wr * 64 + m * 16 + (lane & 15);
                int cb  = (((lane >> 4) << 4) + (kk << 6)) ^ ((row & 7) << 4);
                af[m] = *(const bf8*)(lds + row * 128 + cb);
            }
            #pragma unroll
            for (int n = 0; n < 4; ++n) {
                int row = wc * 64 + n * 16 + (lane & 15);
                int cb  = (((lane >> 4) << 4) + (kk << 6)) ^ ((row & 7) << 4);
                bfr[n] = *(const bf8*)(lds + 16384 + row * 128 + cb);
            }
            #pragma unroll
            for (int m = 0; m < 4; ++m)
                #pragma unroll
                for (int n = 0; n < 4; ++n)
                    acc[m][n] = __builtin_amdgcn_mfma_f32_16x16x32_bf16(
                        af[m], bfr[n], acc[m][n], 0, 0, 0);
        }
    }

    #pragma unroll
    for (int m = 0; m < 4; ++m)
        #pragma unroll
        for (int r = 0; r < 4; ++r) {
            int grow = m0 + wr * 64 + m * 16 + (lane >> 4) * 4 + r;
            #pragma unroll
            for (int n = 0; n < 4; ++n) {
                int gcol = n0 + wc * 64 + n * 16 + (lane & 15);
                C[(size_t)grow * 512 + gcol] = acc[m][n][r];
            }
        }
}

// ---------------------------------------------------------------------------
// fp32 tiled GEMM (small precomputes). EPI 0: store. EPI 4: +p0[m]*p2[n]+p3[n]
// ---------------------------------------------------------------------------
template<int EPI>
__global__ __launch_bounds__(256) void gemm_k(
    const float* __restrict__ A, int lda,
    const float* __restrict__ Bm, int ldb,
    float* __restrict__ C, int ldc,
    int M, int N, int K,
    const float* __restrict__ p0, const float* __restrict__ p2,
    const float* __restrict__ p3)
{
    __shared__ float As[BKK][TILE];
    __shared__ float Bs[BKK][TILE];
    const int tid = threadIdx.x;
    const int tx = tid & 15, ty = tid >> 4;
    const int m0 = blockIdx.y * TILE, n0 = blockIdx.x * TILE;

    float acc[8][8];
    #pragma unroll
    for (int i = 0; i < 8; ++i)
        #pragma unroll
        for (int j = 0; j < 8; ++j) acc[i][j] = 0.f;

    const int arow = tid >> 1;
    const int ak0  = (tid & 1) * 4;
    const int bkr  = tid >> 5;
    const int bcol = (tid & 31) * 4;
    const float* Arow = A + (size_t)(m0 + arow) * lda;

    for (int k0 = 0; k0 < K; k0 += BKK) {
        #pragma unroll
        for (int j = 0; j < 4; ++j) {
            int k = k0 + ak0 + j;
            As[ak0 + j][arow] = (k < K) ? Arow[k] : 0.f;
        }
        {
            int kb = k0 + bkr;
            const float* Brow = Bm + (size_t)kb * ldb + n0;
            #pragma unroll
            for (int j = 0; j < 4; ++j) {
                int n = n0 + bcol + j;
                Bs[bkr][bcol + j] = (kb < K && n < N) ? Brow[bcol + j] : 0.f;
            }
        }
        __syncthreads();
        #pragma unroll
        for (int kk = 0; kk < BKK; ++kk) {
            float4 a0 = *(const float4*)&As[kk][ty * 8];
            float4 a1 = *(const float4*)&As[kk][ty * 8 + 4];
            float4 b0 = *(const float4*)&Bs[kk][tx * 8];
            float4 b1 = *(const float4*)&Bs[kk][tx * 8 + 4];
            float ar[8] = {a0.x,a0.y,a0.z,a0.w,a1.x,a1.y,a1.z,a1.w};
            float br[8] = {b0.x,b0.y,b0.z,b0.w,b1.x,b1.y,b1.z,b1.w};
            #pragma unroll
            for (int i = 0; i < 8; ++i)
                #pragma unroll
                for (int j = 0; j < 8; ++j)
                    acc[i][j] = fmaf(ar[i], br[j], acc[i][j]);
        }
        __syncthreads();
    }

    #pragma unroll
    for (int i = 0; i < 8; ++i) {
        size_t m = (size_t)m0 + ty * 8 + i;
        #pragma unroll
        for (int j = 0; j < 8; ++j) {
            int n = n0 + tx * 8 + j;
            if (n >= N) continue;
            size_t idx = m * (size_t)ldc + n;
            float v = acc[i][j];
            if constexpr (EPI == 0) C[idx] = v;
            else                    C[idx] = v + p0[m] * p2[n] + p3[n];
        }
    }
}

// out = x0 + sum c_j k_j ; in-place safe (elementwise)
__global__ __launch_bounds__(256) void axpy5(
    float4* __restrict__ outf, const float4* __restrict__ x0,
    const float4* __restrict__ k0, const float4* __restrict__ k1,
    const float4* __restrict__ k2, const float4* __restrict__ k3,
    const float4* __restrict__ k4,
    float c0, float c1, float c2, float c3, float c4,
    int nk, int n4)
{
    int i = blockIdx.x * 256 + threadIdx.x;
    if (i >= n4) return;
    float4 r = x0[i];
    if (nk > 0) r = ax4(r, k0[i], c0);
    if (nk > 1) r = ax4(r, k1[i], c1);
    if (nk > 2) r = ax4(r, k2[i], c2);
    if (nk > 3) r = ax4(r, k3[i], c3);
    if (nk > 4) r = ax4(r, k4[i], c4);
    outf[i] = r;
}

__global__ __launch_bounds__(256) void outer_bias(
    float* __restrict__ gc, const float* __restrict__ cond,
    const float* __restrict__ wrow, const float* __restrict__ bias)
{
    int i = blockIdx.x * 256 + threadIdx.x;
    int b = i >> 9, h = i & 511;
    gc[i] = fmaf(cond[b], wrow[h], bias[h]);
}

// Bt[n][k] = bf16(in[k][N... ]) transpose+pad:  out[n*Kpad+k] = in[k*N+n]
__global__ __launch_bounds__(256) void convtrans(
    short* __restrict__ out, const float* __restrict__ in,
    int K, int N, int Kpad, int total)
{
    int i = blockIdx.x * 256 + threadIdx.x;
    if (i >= total) return;
    int n = i / Kpad, k = i - n * Kpad;
    out[i] = (k < K && n < N) ? f2bf(in[(size_t)k * N + n]) : (short)0;
}

// out[n*Kpad+k] = bf16(in[n*K+k])  (no transpose, pad K)
__global__ __launch_bounds__(256) void padbf(
    short* __restrict__ out, const float* __restrict__ in,
    int K, int Kpad, int total)
{
    int i = blockIdx.x * 256 + threadIdx.x;
    if (i >= total) return;
    int n = i / Kpad, k = i - n * Kpad;
    out[i] = (k < K) ? f2bf(in[(size_t)n * K + k]) : (short)0;
}

__global__ __launch_bounds__(256) void padconv(
    float* __restrict__ outf, short* __restrict__ outb,
    const float* __restrict__ in, int D, int Dpad, int total)
{
    int i = blockIdx.x * 256 + threadIdx.x;
    if (i >= total) return;
    int b = i / Dpad, d = i - b * Dpad;
    float v = (d < D) ? in[(size_t)b * D + d] : 0.f;
    if (outf) outf[i] = v;
    outb[i] = f2bf(v);
}

__global__ __launch_bounds__(256) void padvec(
    float* __restrict__ out, const float* __restrict__ in, int N, int Npad)
{
    int i = blockIdx.x * 256 + threadIdx.x;
    if (i < Npad) out[i] = (i < N) ? in[i] : 0.f;
}

// b31[n] = sum_d b3[d] * W1[d][n]
__global__ __launch_bounds__(256) void b31k(
    float* __restrict__ b31, const float* __restrict__ b3,
    const float* __restrict__ W1, int D)
{
    int n = blockIdx.x * 256 + threadIdx.x;
    if (n >= 512) return;
    float s = 0.f;
    for (int d = 0; d < D; ++d) s = fmaf(b3[d], W1[(size_t)d * 512 + n], s);
    b31[n] = s;
}

__global__ __launch_bounds__(256) void final_reduce(
    const float* __restrict__ z, const float* __restrict__ L,
    float* __restrict__ acc, int Dpad, int Dtrue)
{
    __shared__ float ps[4];
    int wave = threadIdx.x >> 6, lane = threadIdx.x & 63;
    int row = blockIdx.x * 4 + wave;
    const float* zp = z + (size_t)row * Dpad;
    float s = 0.f;
    for (int d = lane; d < Dpad; d += 64) { float x = zp[d]; s = fmaf(x, x, s); }
    #pragma unroll
    for (int off = 32; off; off >>= 1) s += __shfl_down(s, off, 64);
    if (lane == 0) ps[wave] = -0.5f * s - 0.5f * (float)Dtrue * LOG2PI + L[row];
    __syncthreads();
    if (threadIdx.x == 0) atomicAdd(acc, ps[0] + ps[1] + ps[2] + ps[3]);
}

__global__ void finalize_k(float* __restrict__ out, const float* __restrict__ acc)
{
    out[0] = -(acc[0] + acc[1]) * (1.f / 8192.f);
}

// ---------------------------------------------------------------------------
extern "C" void kernel_launch(void* const* d_in, const int* in_sizes, int n_in,
                              void* d_out, int out_size, void* d_ws, size_t ws_size,
                              hipStream_t stream)
{
    (void)in_sizes; (void)n_in; (void)out_size; (void)ws_size;
    const float* voxel  = (const float*)d_in[0];
    const float* energy = (const float*)d_in[1];
    const float* cond   = (const float*)d_in[2];
    const float* eps_v  = (const float*)d_in[3];
    const float* eps_e  = (const float*)d_in[4];
    const float* Wt[2][5] = {
        {(const float*)d_in[5], (const float*)d_in[6], (const float*)d_in[7], (const float*)d_in[8], (const float*)d_in[9]},
        {(const float*)d_in[11],(const float*)d_in[12],(const float*)d_in[13],(const float*)d_in[14],(const float*)d_in[15]}};
    const float* b3t[2] = {(const float*)d_in[10], (const float*)d_in[16]};

    const int Bn = 8192, H = 512;
    const size_t BH = (size_t)Bn * H;

    // workspace budget: ~188 MB total (proven-safe envelope is ~228 MB; R3's
    // 272 MB overflowed d_ws and memory-faulted)
    char* wp = (char*)d_ws;
    auto alloc = [&](size_t bytes) { char* p = wp; wp += (bytes + 255) & ~(size_t)255; return p; };
    float* th1   = (float*)alloc(BH * 4);
    float* gc    = (float*)alloc(BH * 4);
    float* vbuf  = (float*)alloc(BH * 4);
    float* Pcur  = (float*)alloc(BH * 4);
    float* Pk[5]; for (int i = 0; i < 5; ++i) Pk[i] = (float*)alloc(BH * 4);
    float* xf    = (float*)alloc(BH * 4);
    short* w1t   = (short*)alloc((size_t)512 * 512 * 2);
    short* w2t   = (short*)alloc((size_t)512 * 512 * 2);
    short* w3bt  = (short*)alloc((size_t)512 * 512 * 2);
    short* w3c   = (short*)alloc((size_t)1024 * 512 * 2);
    float* w31f  = (float*)alloc((size_t)512 * 512 * 4);
    short* xb    = (short*)alloc(BH * 2);
    short* epsb  = (short*)alloc(BH * 2);
    float* b3pad = (float*)alloc(512 * 4);
    float* b31   = (float*)alloc(512 * 4);
    float* L     = (float*)alloc(Bn * 4);
    float* acc   = (float*)alloc(256);

    (void)hipMemsetAsync(acc, 0, 2 * sizeof(float), stream);

    static const double AD[6][5] = {
        {0,0,0,0,0},
        {1.0/5,0,0,0,0},
        {3.0/40,9.0/40,0,0,0},
        {44.0/45,-56.0/15,32.0/9,0,0},
        {19372.0/6561,-25360.0/2187,64448.0/6561,-212.0/729,0},
        {9017.0/3168,-355.0/33,46732.0/5247,49.0/176,-5103.0/18656}};
    static const double Bcf[6] = {35.0/384, 0.0, 500.0/1113, 125.0/192, -2187.0/6784, 11.0/84};
    static const double CD[6]  = {0.0, 0.2, 0.3, 0.8, 8.0/9.0, 1.0};
    const double dtd = -0.1;

    for (int flow = 0; flow < 2; ++flow) {
        const int D    = (flow == 0) ? 504 : 45;
        const int Dpad = (flow == 0) ? 512 : 64;
        const float* x_in = (flow == 0) ? voxel : energy;
        const float* eps  = (flow == 0) ? eps_v : eps_e;
        const float* W1 = Wt[flow][0]; const float* b1 = Wt[flow][1];
        const float* W2 = Wt[flow][2]; const float* b2 = Wt[flow][3];
        const float* W3 = Wt[flow][4]; const float* b3 = b3t[flow];
        const float* wtp = W1 + (size_t)D * H;    // t-row of W1
        const int n4h = Bn * H / 4;

        (void)hipMemsetAsync(L, 0, Bn * sizeof(float), stream);

        // ---- weight prep
        convtrans<<<(512 * Dpad + 255) / 256, 256, 0, stream>>>(w1t, W1, D, 512, Dpad, 512 * Dpad);
        convtrans<<<(512 * 512 + 255) / 256, 256, 0, stream>>>(w2t, W2, 512, 512, 512, 512 * 512);
        padbf<<<(512 * Dpad + 255) / 256, 256, 0, stream>>>(w3bt, W3, D, Dpad, 512 * Dpad);
        // w3c rows [0,Dpad): W3^T ; rows [Dpad, Dpad+512): W31^T  (W31 = W3@W1[:D])
        convtrans<<<(Dpad * 512 + 255) / 256, 256, 0, stream>>>(w3c, W3, 512, D, 512, Dpad * 512);
        gemm_k<0><<<dim3(4, 4), 256, 0, stream>>>(W3, D, W1, 512, w31f, 512, 512, 512, D, 0, 0, 0);
        convtrans<<<(512 * 512 + 255) / 256, 256, 0, stream>>>(w3c + (size_t)Dpad * 512, w31f, 512, 512, 512, 512 * 512);
        b31k<<<2, 256, 0, stream>>>(b31, b3, W1, D);
        padvec<<<2, 256, 0, stream>>>(b3pad, b3, D, Dpad);
        padconv<<<(Bn * Dpad + 255) / 256, 256, 0, stream>>>(xf, xb, x_in, D, Dpad, Bn * Dpad);
        padconv<<<(Bn * Dpad + 255) / 256, 256, 0, stream>>>(nullptr, epsb, eps, D, Dpad, Bn * Dpad);

        // ---- precomputes: th1 = eps@W1 ; vbuf = eps@W3^T ; Pcur = x0@W1 ; gc
        mgemm0<<<dim3(4, 64), 256, 0, stream>>>(epsb, w1t, Dpad, th1);
        mgemm0<<<dim3(4, 64), 256, 0, stream>>>(epsb, w3bt, Dpad, vbuf);
        mgemm0<<<dim3(4, 64), 256, 0, stream>>>(xb, w1t, Dpad, Pcur);
        if (flow == 0) {
            gemm_k<4><<<dim3(4, 64), 256, 0, stream>>>(energy, 45, W1 + (size_t)505 * H, H,
                gc, H, Bn, H, 45, cond, W1 + (size_t)550 * H, b1);
        } else {
            outer_bias<<<(int)(BH / 256), 256, 0, stream>>>(gc, cond, W1 + (size_t)46 * H, b1);
        }

        for (int s = 0; s < 10; ++s) {
            float t0f = 1.0f + (float)s * -0.1f;
            for (int i = 0; i < 6; ++i) {
                float ti = t0f + (float)(CD[i] * dtd);
                float c[5] = {0,0,0,0,0};
                for (int j = 0; j < i; ++j) c[j] = (float)(dtd * AD[i][j]);
                float* Pout = (i < 5) ? Pk[i] : Pk[1];   // P1 dead after stage 5 input read (per-block row ownership makes reuse safe)
                float tc = (float)(dtd * Bcf[i]);
                float kc = (float)(dtd * Bcf[i]);        // 0 for i==1
                if (flow == 0)
                    stage_k<512><<<256, 256, 0, stream>>>(Pcur, Pk[0], Pk[1], Pk[2], Pk[3], Pk[4],
                        c[0], c[1], c[2], c[3], c[4], i, gc, th1, vbuf, wtp, b2, b3pad, b31,
                        w2t, w3c, xf, Pout, L, ti, tc, kc);
                else
                    stage_k<64><<<256, 256, 0, stream>>>(Pcur, Pk[0], Pk[1], Pk[2], Pk[3], Pk[4],
                        c[0], c[1], c[2], c[3], c[4], i, gc, th1, vbuf, wtp, b2, b3pad, b31,
                        w2t, w3c, xf, Pout, L, ti, tc, kc);
            }
            // P += dt*(b0 P0 + b2 P2 + b3 P3 + b4 P4 + b5 P5)   (P5 in Pk[1])
            axpy5<<<(n4h + 255) / 256, 256, 0, stream>>>((float4*)Pcur, (const float4*)Pcur,
                (const float4*)Pk[0], (const float4*)Pk[2], (const float4*)Pk[3],
                (const float4*)Pk[4], (const float4*)Pk[1],
                (float)(dtd * Bcf[0]), (float)(dtd * Bcf[2]), (float)(dtd * Bcf[3]),
                (float)(dtd * Bcf[4]), (float)(dtd * Bcf[5]), 5, n4h);
        }
        final_reduce<<<Bn / 4, 256, 0, stream>>>(xf, L, acc + flow, Dpad, D);
    }
    finalize_k<<<1, 1, 0, stream>>>((float*)d_out, acc);
}

// Round 5
// 8610.699 us; speedup vs baseline: 6.5125x; 1.3950x over previous
//
#include <hip/hip_runtime.h>
#include <math.h>
#include <stdint.h>

#define LOG2PI 1.8378770664093453f

typedef __attribute__((ext_vector_type(8))) short bf8;   // 8 bf16 (4 VGPRs)
typedef __attribute__((ext_vector_type(4))) float f4;

__device__ __forceinline__ short f2bf(float f) {
    uint32_t u = __float_as_uint(f);
    u += 0x7fffu + ((u >> 16) & 1u);          // RNE
    return (short)(u >> 16);
}
__device__ __forceinline__ float bf2f(unsigned short u) {
    return __uint_as_float(((uint32_t)u) << 16);
}
__device__ __forceinline__ void gload16(const void* g, void* l) {
    __builtin_amdgcn_global_load_lds(
        (const __attribute__((address_space(1))) uint32_t*)(uintptr_t)g,
        (__attribute__((address_space(3))) uint32_t*)(uintptr_t)l, 16, 0, 0);
}
__device__ __forceinline__ void addbf4(float4& p, short4 q, float c) {
    p.x = fmaf(c, bf2f((unsigned short)q.x), p.x);
    p.y = fmaf(c, bf2f((unsigned short)q.y), p.y);
    p.z = fmaf(c, bf2f((unsigned short)q.z), p.z);
    p.w = fmaf(c, bf2f((unsigned short)q.w), p.w);
}

// ---------------------------------------------------------------------------
// Fused FFJORD stage kernel. 256 blocks x 512 threads (8 waves) x 32 rows.
// Phase B: pre1 = Pcur + sum c_j P_j + ti*wt  (gc,b1 folded into Pcur);
//          a1 = tanh(pre1) -> LDS rows 0..31; ta1 = (1-a1^2)*th1 -> rows 32..63
// Phase C: [a1;ta1] @ W2 (K=512, 64 cols/wave). val -> a2=tanh(+b2) -> LDS;
//          tan -> ta2=(1-a2^2)*tan; trace += ta2 . vbuf -> atomicAdd L
// Phase D: a2 @ [W3 | W31] (NTOT = DPAD+512):
//          col<DPAD  -> xf += kcoef*(acc+b3)
//          col>=DPAD -> P_i = acc+b31 (bf16), or if FINAL: Pcur = Pcur+sum db*P
// ---------------------------------------------------------------------------
template<int DPAD, bool FINAL>
__global__ __launch_bounds__(512, 2) void stage_k(
    float* Pcur,
    const short* __restrict__ P0, const short* __restrict__ P1,
    const short* __restrict__ P2, const short* __restrict__ P3,
    const short* __restrict__ P4,
    float c0, float c1, float c2, float c3, float c4, int nk,
    const short* __restrict__ th1b, const short* __restrict__ vbufb,
    const float* __restrict__ wt, const float* __restrict__ b2,
    const float* __restrict__ b3p, const float* __restrict__ b31,
    const short* __restrict__ w2t, const short* __restrict__ w3c,
    float* __restrict__ xf, short* __restrict__ Pout,
    float* __restrict__ L, float ti, float tcoef, float kcoef,
    float db0, float db2, float db3, float db4, float db5)
{
    __shared__ char lds[65536];   // [64 rows][512 bf16] a1|ta1; a2 overlays rows 0..31
    const int tid = threadIdx.x, wave = tid >> 6, lane = tid & 63;
    const int m0 = blockIdx.x * 32;

    // ---------------- Phase B ----------------
    #pragma unroll
    for (int it = 0; it < 8; ++it) {
        int e = (it << 9) + tid;            // 0..4095
        int row = e >> 7, cc = e & 127;
        size_t gi = ((size_t)(m0 + row) << 7) + cc;
        float4 p = ((const float4*)Pcur)[gi];
        if (nk > 0) addbf4(p, ((const short4*)P0)[gi], c0);
        if (nk > 1) addbf4(p, ((const short4*)P1)[gi], c1);
        if (nk > 2) addbf4(p, ((const short4*)P2)[gi], c2);
        if (nk > 3) addbf4(p, ((const short4*)P3)[gi], c3);
        if (nk > 4) addbf4(p, ((const short4*)P4)[gi], c4);
        float4 w = ((const float4*)wt)[cc];
        short4 t4 = ((const short4*)th1b)[gi];
        float ax = tanhf(fmaf(ti, w.x, p.x));
        float ay = tanhf(fmaf(ti, w.y, p.y));
        float az = tanhf(fmaf(ti, w.z, p.z));
        float aw = tanhf(fmaf(ti, w.w, p.w));
        short4 s1; s1.x = f2bf(ax); s1.y = f2bf(ay); s1.z = f2bf(az); s1.w = f2bf(aw);
        short4 s2;
        s2.x = f2bf((1.f - ax * ax) * bf2f((unsigned short)t4.x));
        s2.y = f2bf((1.f - ay * ay) * bf2f((unsigned short)t4.y));
        s2.z = f2bf((1.f - az * az) * bf2f((unsigned short)t4.z));
        s2.w = f2bf((1.f - aw * aw) * bf2f((unsigned short)t4.w));
        int base = (row << 10) + ((cc << 3) ^ ((row & 7) << 4));
        *(short4*)(lds + base) = s1;
        *(short4*)(lds + 32768 + base) = s2;
    }
    __syncthreads();

    // ---------------- Phase C: [a1;ta1](64) @ W2, 64 cols/wave, K=512 ------
    f4 acc[4][4];
    #pragma unroll
    for (int mt = 0; mt < 4; ++mt)
        #pragma unroll
        for (int nt = 0; nt < 4; ++nt) acc[mt][nt] = (f4)0.0f;
    {
        const short* wb = w2t + ((size_t)((wave << 6) + (lane & 15)) << 9) + ((lane >> 4) << 3);
        bf8 bcur[4], bnxt[4];
        #pragma unroll
        for (int nt = 0; nt < 4; ++nt) bcur[nt] = *(const bf8*)(wb + (nt << 13));
        for (int kt = 0; kt < 16; ++kt) {
            bf8 af[4];
            int kb = (kt << 6) + ((lane >> 4) << 4);
            #pragma unroll
            for (int mt = 0; mt < 4; ++mt) {
                int row = (mt << 4) + (lane & 15);
                af[mt] = *(const bf8*)(lds + (row << 10) + (kb ^ ((row & 7) << 4)));
            }
            if (kt < 15) {
                #pragma unroll
                for (int nt = 0; nt < 4; ++nt)
                    bnxt[nt] = *(const bf8*)(wb + (nt << 13) + ((kt + 1) << 5));
            }
            #pragma unroll
            for (int mt = 0; mt < 4; ++mt)
                #pragma unroll
                for (int nt = 0; nt < 4; ++nt)
                    acc[mt][nt] = __builtin_amdgcn_mfma_f32_16x16x32_bf16(
                        af[mt], bcur[nt], acc[mt][nt], 0, 0, 0);
            #pragma unroll
            for (int nt = 0; nt < 4; ++nt) bcur[nt] = bnxt[nt];
        }
    }
    __syncthreads();   // all a1/ta1 reads done before a2 overlay

    // ---------------- Phase C epilogue: a2 -> LDS, trace -> L --------------
    float trp[2][4] = {{0.f,0.f,0.f,0.f},{0.f,0.f,0.f,0.f}};
    #pragma unroll
    for (int mt = 0; mt < 2; ++mt) {
        #pragma unroll
        for (int nt = 0; nt < 4; ++nt) {
            int col = (wave << 6) + (nt << 4) + (lane & 15);
            float bb = b2[col];
            #pragma unroll
            for (int r = 0; r < 4; ++r) {
                int row = (mt << 4) + ((lane >> 4) << 2) + r;
                float a = tanhf(acc[mt][nt][r] + bb);
                *(short*)(lds + (row << 10) + ((col << 1) ^ ((row & 7) << 4))) = f2bf(a);
                float ta2 = (1.f - a * a) * acc[mt + 2][nt][r];
                trp[mt][r] = fmaf(ta2,
                    bf2f((unsigned short)vbufb[((size_t)(m0 + row) << 9) + col]),
                    trp[mt][r]);
            }
        }
    }
    if (tcoef != 0.f) {
        #pragma unroll
        for (int mt = 0; mt < 2; ++mt)
            #pragma unroll
            for (int r = 0; r < 4; ++r) {
                float s = trp[mt][r];
                s += __shfl_xor(s, 1); s += __shfl_xor(s, 2);
                s += __shfl_xor(s, 4); s += __shfl_xor(s, 8);
                trp[mt][r] = s;
            }
        if ((lane & 15) == 0) {
            #pragma unroll
            for (int mt = 0; mt < 2; ++mt)
                #pragma unroll
                for (int r = 0; r < 4; ++r) {
                    int row = (mt << 4) + ((lane >> 4) << 2) + r;
                    atomicAdd(&L[m0 + row], tcoef * trp[mt][r]);
                }
        }
    }
    __syncthreads();   // a2 visible

    // ---------------- Phase D: a2 @ [W3|W31] ----------------
    constexpr int NWT  = (DPAD == 512) ? 8 : 5;   // 16-col tiles per wave
    constexpr int NTOT = DPAD + 512;
    f4 acc2[2][NWT];
    #pragma unroll
    for (int mt = 0; mt < 2; ++mt)
        #pragma unroll
        for (int nt = 0; nt < NWT; ++nt) acc2[mt][nt] = (f4)0.0f;
    {
        const short* wb3 = w3c + ((size_t)((wave * NWT << 4) + (lane & 15)) << 9) + ((lane >> 4) << 3);
        bf8 bcur[NWT], bnxt[NWT];
        #pragma unroll
        for (int nt = 0; nt < NWT; ++nt) bcur[nt] = *(const bf8*)(wb3 + (nt << 13));
        for (int kt = 0; kt < 16; ++kt) {
            bf8 af[2];
            int kb = (kt << 6) + ((lane >> 4) << 4);
            #pragma unroll
            for (int mt = 0; mt < 2; ++mt) {
                int row = (mt << 4) + (lane & 15);
                af[mt] = *(const bf8*)(lds + (row << 10) + (kb ^ ((row & 7) << 4)));
            }
            if (kt < 15) {
                #pragma unroll
                for (int nt = 0; nt < NWT; ++nt)
                    bnxt[nt] = *(const bf8*)(wb3 + (nt << 13) + ((kt + 1) << 5));
            }
            #pragma unroll
            for (int mt = 0; mt < 2; ++mt)
                #pragma unroll
                for (int nt = 0; nt < NWT; ++nt)
                    acc2[mt][nt] = __builtin_amdgcn_mfma_f32_16x16x32_bf16(
                        af[mt], bcur[nt], acc2[mt][nt], 0, 0, 0);
            #pragma unroll
            for (int nt = 0; nt < NWT; ++nt) bcur[nt] = bnxt[nt];
        }
    }
    #pragma unroll
    for (int mt = 0; mt < 2; ++mt) {
        #pragma unroll
        for (int nt = 0; nt < NWT; ++nt) {
            int col = (wave * NWT << 4) + (nt << 4) + (lane & 15);
            #pragma unroll
            for (int r = 0; r < 4; ++r) {
                int row = (mt << 4) + ((lane >> 4) << 2) + r;
                size_t grow = (size_t)(m0 + row);
                float v = acc2[mt][nt][r];
                if (col < DPAD) {
                    if (kcoef != 0.f) {
                        size_t xi = grow * DPAD + col;
                        xf[xi] = fmaf(kcoef, v + b3p[col], xf[xi]);
                    }
                } else if (col < NTOT) {
                    int colh = col - DPAD;
                    size_t pi = (grow << 9) + colh;
                    float pv = v + b31[colh];
                    if constexpr (FINAL) {
                        float pn = Pcur[pi];
                        pn = fmaf(db0, bf2f((unsigned short)P0[pi]), pn);
                        pn = fmaf(db2, bf2f((unsigned short)P2[pi]), pn);
                        pn = fmaf(db3, bf2f((unsigned short)P3[pi]), pn);
                        pn = fmaf(db4, bf2f((unsigned short)P4[pi]), pn);
                        pn = fmaf(db5, pv, pn);
                        Pcur[pi] = pn;
                    } else {
                        Pout[pi] = f2bf(pv);
                    }
                }
            }
        }
    }
}

// ---------------------------------------------------------------------------
// bf16 MFMA GEMM (precomputes): out(M x 512) = A(M x K) @ Bt(512 x K)^T + bias
// OUT 0: f32 store; OUT 1: bf16 store. K%64==0, M%128==0, grid (4, M/128).
// ---------------------------------------------------------------------------
template<int OUT>
__global__ __launch_bounds__(256) void mgemm0(
    const short* __restrict__ A, const short* __restrict__ Bt, int K,
    float* __restrict__ Cf, short* __restrict__ Cb,
    const float* __restrict__ bias)
{
    __shared__ char lds[32768];
    const int tid = threadIdx.x, wave = tid >> 6, lane = tid & 63;
    const int m0 = blockIdx.y * 128, n0 = blockIdx.x * 128;
    const int wr = wave >> 1, wc = wave & 1;

    f4 acc[4][4];
    #pragma unroll
    for (int m = 0; m < 4; ++m)
        #pragma unroll
        for (int n = 0; n < 4; ++n) acc[m][n] = (f4)0.0f;

    const int cbs  = (((lane & 7) ^ (lane >> 3)) << 4);
    const int lrow = lane >> 3;

    for (int k0 = 0; k0 < K; k0 += 64) {
        __syncthreads();
        #pragma unroll
        for (int i = 0; i < 4; ++i) {
            int q = wave * 4 + i;
            int row = q * 8 + lrow;
            gload16((const char*)(A  + (size_t)(m0 + row) * K + k0) + cbs, lds + q * 1024);
            gload16((const char*)(Bt + (size_t)(n0 + row) * K + k0) + cbs, lds + 16384 + q * 1024);
        }
        __syncthreads();
        #pragma unroll
        for (int kk = 0; kk < 2; ++kk) {
            bf8 af[4], bfr[4];
            #pragma unroll
            for (int m = 0; m < 4; ++m) {
                int row = wr * 64 + m * 16 + (lane & 15);
                int cb  = (((lane >> 4) << 4) + (kk << 6)) ^ ((row & 7) << 4);
                af[m] = *(const bf8*)(lds + row * 128 + cb);
            }
            #pragma unroll
            for (int n = 0; n < 4; ++n) {
                int row = wc * 64 + n * 16 + (lane & 15);
                int cb  = (((lane >> 4) << 4) + (kk << 6)) ^ ((row & 7) << 4);
                bfr[n] = *(const bf8*)(lds + 16384 + row * 128 + cb);
            }
            #pragma unroll
            for (int m = 0; m < 4; ++m)
                #pragma unroll
                for (int n = 0; n < 4; ++n)
                    acc[m][n] = __builtin_amdgcn_mfma_f32_16x16x32_bf16(
                        af[m], bfr[n], acc[m][n], 0, 0, 0);
        }
    }

    #pragma unroll
    for (int m = 0; m < 4; ++m)
        #pragma unroll
        for (int r = 0; r < 4; ++r) {
            int grow = m0 + wr * 64 + m * 16 + (lane >> 4) * 4 + r;
            #pragma unroll
            for (int n = 0; n < 4; ++n) {
                int gcol = n0 + wc * 64 + n * 16 + (lane & 15);
                float v = acc[m][n][r];
                if (bias) v += bias[gcol];
                if constexpr (OUT == 0) Cf[(size_t)grow * 512 + gcol] = v;
                else                    Cb[(size_t)grow * 512 + gcol] = f2bf(v);
            }
        }
}

// ---------------------------------------------------------------------------
// prep kernels
// ---------------------------------------------------------------------------
// w1x[n][k]: k<D -> W1[k][n]; k in [Dpad,Dpad+..): j<extN -> W1[rowE+j][n],
// j==extN -> W1[rowC][n]; else 0.  (t-row excluded)
__global__ __launch_bounds__(256) void buildw1x(
    short* __restrict__ out, const float* __restrict__ W1,
    int D, int Dpad, int Kext, int extN, int rowE, int rowC, int total)
{
    int i = blockIdx.x * 256 + threadIdx.x;
    if (i >= total) return;
    int n = i / Kext, k = i - n * Kext;
    float v = 0.f;
    if (k < D) v = W1[(size_t)k * 512 + n];
    else if (k >= Dpad) {
        int j = k - Dpad;
        if (j < extN)       v = W1[(size_t)(rowE + j) * 512 + n];
        else if (j == extN) v = W1[(size_t)rowC * 512 + n];
    }
    out[i] = f2bf(v);
}

// ab[b][k]: k<D -> x[b][k]; ext: j<extN -> e[b][j]; j==extN -> c[b]; else 0
__global__ __launch_bounds__(256) void buildab(
    short* __restrict__ out, const float* __restrict__ x,
    const float* __restrict__ e, const float* __restrict__ c,
    int D, int Dpad, int Kext, int extN, int total)
{
    int i = blockIdx.x * 256 + threadIdx.x;
    if (i >= total) return;
    int b = i / Kext, k = i - b * Kext;
    float v = 0.f;
    if (k < D) v = x[(size_t)b * D + k];
    else if (k >= Dpad) {
        int j = k - Dpad;
        if (e && j < extN)       v = e[(size_t)b * 45 + j];
        else if (c && j == extN) v = c[b];
    }
    out[i] = f2bf(v);
}

// out[n*Kpad+k] = bf16(in[n*K+k])  (no transpose, pad K)
__global__ __launch_bounds__(256) void padbf(
    short* __restrict__ out, const float* __restrict__ in,
    int K, int Kpad, int total)
{
    int i = blockIdx.x * 256 + threadIdx.x;
    if (i >= total) return;
    int n = i / Kpad, k = i - n * Kpad;
    out[i] = (k < K) ? f2bf(in[(size_t)n * K + k]) : (short)0;
}

// out[n*Kpad+k] = bf16(in[k*N+n]) transpose+pad
__global__ __launch_bounds__(256) void convtrans(
    short* __restrict__ out, const float* __restrict__ in,
    int K, int N, int Kpad, int total)
{
    int i = blockIdx.x * 256 + threadIdx.x;
    if (i >= total) return;
    int n = i / Kpad, k = i - n * Kpad;
    out[i] = (k < K && n < N) ? f2bf(in[(size_t)k * N + n]) : (short)0;
}

__global__ __launch_bounds__(256) void padx(
    float* __restrict__ out, const float* __restrict__ in,
    int D, int Dpad, int total)
{
    int i = blockIdx.x * 256 + threadIdx.x;
    if (i >= total) return;
    int b = i / Dpad, d = i - b * Dpad;
    out[i] = (d < D) ? in[(size_t)b * D + d] : 0.f;
}

__global__ __launch_bounds__(256) void padvec(
    float* __restrict__ out, const float* __restrict__ in, int N, int Npad)
{
    int i = blockIdx.x * 256 + threadIdx.x;
    if (i < Npad) out[i] = (i < N) ? in[i] : 0.f;
}

// b31[n] = sum_d b3[d] * W1[d][n]
__global__ __launch_bounds__(256) void b31k(
    float* __restrict__ b31, const float* __restrict__ b3,
    const float* __restrict__ W1, int D)
{
    int n = blockIdx.x * 256 + threadIdx.x;
    if (n >= 512) return;
    float s = 0.f;
    for (int d = 0; d < D; ++d) s = fmaf(b3[d], W1[(size_t)d * 512 + n], s);
    b31[n] = s;
}

__global__ __launch_bounds__(256) void final_reduce(
    const float* __restrict__ z, const float* __restrict__ L,
    float* __restrict__ acc, int Dpad, int Dtrue)
{
    __shared__ float ps[4];
    int wave = threadIdx.x >> 6, lane = threadIdx.x & 63;
    int row = blockIdx.x * 4 + wave;
    const float* zp = z + (size_t)row * Dpad;
    float s = 0.f;
    for (int d = lane; d < Dpad; d += 64) { float x = zp[d]; s = fmaf(x, x, s); }
    #pragma unroll
    for (int off = 32; off; off >>= 1) s += __shfl_down(s, off, 64);
    if (lane == 0) ps[wave] = -0.5f * s - 0.5f * (float)Dtrue * LOG2PI + L[row];
    __syncthreads();
    if (threadIdx.x == 0) atomicAdd(acc, ps[0] + ps[1] + ps[2] + ps[3]);
}

__global__ void finalize_k(float* __restrict__ out, const float* __restrict__ acc)
{
    out[0] = -(acc[0] + acc[1]) * (1.f / 8192.f);
}

// ---------------------------------------------------------------------------
extern "C" void kernel_launch(void* const* d_in, const int* in_sizes, int n_in,
                              void* d_out, int out_size, void* d_ws, size_t ws_size,
                              hipStream_t stream)
{
    (void)in_sizes; (void)n_in; (void)out_size; (void)ws_size;
    const float* voxel  = (const float*)d_in[0];
    const float* energy = (const float*)d_in[1];
    const float* cond   = (const float*)d_in[2];
    const float* eps_v  = (const float*)d_in[3];
    const float* eps_e  = (const float*)d_in[4];
    const float* Wt[2][5] = {
        {(const float*)d_in[5], (const float*)d_in[6], (const float*)d_in[7], (const float*)d_in[8], (const float*)d_in[9]},
        {(const float*)d_in[11],(const float*)d_in[12],(const float*)d_in[13],(const float*)d_in[14],(const float*)d_in[15]}};
    const float* b3t[2] = {(const float*)d_in[10], (const float*)d_in[16]};

    const int Bn = 8192, H = 512;
    const size_t BH = (size_t)Bn * H;

    // workspace ~115 MB (safe envelope ~228 MB)
    char* wp = (char*)d_ws;
    auto alloc = [&](size_t bytes) { char* p = wp; wp += (bytes + 255) & ~(size_t)255; return p; };
    float* Pcur  = (float*)alloc(BH * 4);
    short* th1b  = (short*)alloc(BH * 2);
    short* vbufb = (short*)alloc(BH * 2);
    short* Pk[5]; for (int i = 0; i < 5; ++i) Pk[i] = (short*)alloc(BH * 2);
    float* xf    = (float*)alloc(BH * 4);
    short* abx   = (short*)alloc((size_t)Bn * 576 * 2);
    short* abeps = (short*)alloc((size_t)Bn * 576 * 2);
    short* w1x   = (short*)alloc((size_t)512 * 576 * 2);
    short* w2t   = (short*)alloc((size_t)512 * 512 * 2);
    short* w3bt  = (short*)alloc((size_t)512 * 576 * 2);
    short* w3c   = (short*)alloc((size_t)1024 * 512 * 2);
    float* w31f  = (float*)alloc((size_t)512 * 512 * 4);
    float* b3pad = (float*)alloc(512 * 4);
    float* b31   = (float*)alloc(512 * 4);
    float* L     = (float*)alloc(Bn * 4);
    float* acc   = (float*)alloc(256);

    (void)hipMemsetAsync(acc, 0, 2 * sizeof(float), stream);

    static const double AD[6][5] = {
        {0,0,0,0,0},
        {1.0/5,0,0,0,0},
        {3.0/40,9.0/40,0,0,0},
        {44.0/45,-56.0/15,32.0/9,0,0},
        {19372.0/6561,-25360.0/2187,64448.0/6561,-212.0/729,0},
        {9017.0/3168,-355.0/33,46732.0/5247,49.0/176,-5103.0/18656}};
    static const double Bcf[6] = {35.0/384, 0.0, 500.0/1113, 125.0/192, -2187.0/6784, 11.0/84};
    static const double CD[6]  = {0.0, 0.2, 0.3, 0.8, 8.0/9.0, 1.0};
    const double dtd = -0.1;

    for (int flow = 0; flow < 2; ++flow) {
        const int D    = (flow == 0) ? 504 : 45;
        const int Dpad = (flow == 0) ? 512 : 64;
        const int Kext = Dpad + 64;              // 576 / 128
        const int extN = (flow == 0) ? 45 : 0;
        const int rowE = (flow == 0) ? 505 : 0;
        const int rowC = (flow == 0) ? 550 : 46;
        const float* x_in = (flow == 0) ? voxel : energy;
        const float* eps  = (flow == 0) ? eps_v : eps_e;
        const float* ecnd = (flow == 0) ? energy : nullptr;
        const float* W1 = Wt[flow][0]; const float* b1 = Wt[flow][1];
        const float* W2 = Wt[flow][2]; const float* b2 = Wt[flow][3];
        const float* W3 = Wt[flow][4]; const float* b3 = b3t[flow];
        const float* wtp = W1 + (size_t)D * H;    // t-row of W1

        (void)hipMemsetAsync(L, 0, Bn * sizeof(float), stream);

        // ---- prep
        buildw1x<<<(512 * Kext + 255) / 256, 256, 0, stream>>>(
            w1x, W1, D, Dpad, Kext, extN, rowE, rowC, 512 * Kext);
        buildab<<<(Bn * Kext + 255) / 256, 256, 0, stream>>>(
            abx, x_in, ecnd, cond, D, Dpad, Kext, extN, Bn * Kext);
        buildab<<<(Bn * Kext + 255) / 256, 256, 0, stream>>>(
            abeps, eps, nullptr, nullptr, D, Dpad, Kext, extN, Bn * Kext);
        padbf<<<(512 * Kext + 255) / 256, 256, 0, stream>>>(w3bt, W3, D, Kext, 512 * Kext);
        convtrans<<<(512 * 512 + 255) / 256, 256, 0, stream>>>(w2t, W2, 512, 512, 512, 512 * 512);
        // w31f = W3 @ W1[:D]  (bf16 MFMA; ext slots are zero in w3bt)
        mgemm0<0><<<dim3(4, 4), 256, 0, stream>>>(w3bt, w1x, Kext, w31f, nullptr, nullptr);
        // w3c rows [0,Dpad): W3^T ; rows [Dpad,Dpad+512): W31^T
        convtrans<<<(Dpad * 512 + 255) / 256, 256, 0, stream>>>(w3c, W3, 512, D, 512, Dpad * 512);
        convtrans<<<(512 * 512 + 255) / 256, 256, 0, stream>>>(
            w3c + (size_t)Dpad * 512, w31f, 512, 512, 512, 512 * 512);
        b31k<<<2, 256, 0, stream>>>(b31, b3, W1, D);
        padvec<<<2, 256, 0, stream>>>(b3pad, b3, D, Dpad);
        padx<<<(Bn * Dpad + 255) / 256, 256, 0, stream>>>(xf, x_in, D, Dpad, Bn * Dpad);

        // ---- precomputes: Pcur = [x|e,c]@W1ext + b1 ; th1 = eps@W1 ; vbuf = eps@W3^T
        mgemm0<0><<<dim3(4, 64), 256, 0, stream>>>(abx, w1x, Kext, Pcur, nullptr, b1);
        mgemm0<1><<<dim3(4, 64), 256, 0, stream>>>(abeps, w1x, Kext, nullptr, th1b, nullptr);
        mgemm0<1><<<dim3(4, 64), 256, 0, stream>>>(abeps, w3bt, Kext, nullptr, vbufb, nullptr);

        const float db0 = (float)(dtd * Bcf[0]), db2 = (float)(dtd * Bcf[2]),
                    db3 = (float)(dtd * Bcf[3]), db4 = (float)(dtd * Bcf[4]),
                    db5 = (float)(dtd * Bcf[5]);

        for (int s = 0; s < 10; ++s) {
            float t0f = 1.0f + (float)s * -0.1f;
            for (int i = 0; i < 6; ++i) {
                float ti = t0f + (float)(CD[i] * dtd);
                float c[5] = {0,0,0,0,0};
                for (int j = 0; j < i; ++j) c[j] = (float)(dtd * AD[i][j]);
                float tc = (float)(dtd * Bcf[i]);   // 0 for i==1
                if (flow == 0) {
                    if (i < 5)
                        stage_k<512, false><<<256, 512, 0, stream>>>(Pcur,
                            Pk[0], Pk[1], Pk[2], Pk[3], Pk[4],
                            c[0], c[1], c[2], c[3], c[4], i, th1b, vbufb, wtp, b2,
                            b3pad, b31, w2t, w3c, xf, Pk[i], L, ti, tc, tc,
                            0.f, 0.f, 0.f, 0.f, 0.f);
                    else
                        stage_k<512, true><<<256, 512, 0, stream>>>(Pcur,
                            Pk[0], Pk[1], Pk[2], Pk[3], Pk[4],
                            c[0], c[1], c[2], c[3], c[4], i, th1b, vbufb, wtp, b2,
                            b3pad, b31, w2t, w3c, xf, nullptr, L, ti, tc, tc,
                            db0, db2, db3, db4, db5);
                } else {
                    if (i < 5)
                        stage_k<64, false><<<256, 512, 0, stream>>>(Pcur,
                            Pk[0], Pk[1], Pk[2], Pk[3], Pk[4],
                            c[0], c[1], c[2], c[3], c[4], i, th1b, vbufb, wtp, b2,
                            b3pad, b31, w2t, w3c, xf, Pk[i], L, ti, tc, tc,
                            0.f, 0.f, 0.f, 0.f, 0.f);
                    else
                        stage_k<64, true><<<256, 512, 0, stream>>>(Pcur,
                            Pk[0], Pk[1], Pk[2], Pk[3], Pk[4],
                            c[0], c[1], c[2], c[3], c[4], i, th1b, vbufb, wtp, b2,
                            b3pad, b31, w2t, w3c, xf, nullptr, L, ti, tc, tc,
                            db0, db2, db3, db4, db5);
                }
            }
        }
        final_reduce<<<Bn / 4, 256, 0, stream>>>(xf, L, acc + flow, Dpad, D);
    }
    finalize_k<<<1, 1, 0, stream>>>((float*)d_out, acc);
}